// Round 8
// baseline (226.013 us; speedup 1.0000x reference)
//
#include <hip/hip_runtime.h>
#include <hip/hip_bf16.h>
#include <math.h>

#define LSEQ 320
#define CS 384
#define CZ 128
#define CH 16
#define NH 12
#define PQ 4
#define PV 8
#define EPSF 1e-8f

typedef short short8 __attribute__((ext_vector_type(8)));
typedef float f32x4 __attribute__((ext_vector_type(4)));
typedef unsigned short ush2 __attribute__((ext_vector_type(2)));

// float -> bf16 (RNE)
__device__ __forceinline__ unsigned short f2b(float x) {
    union { float f; unsigned u; } v; v.f = x;
    unsigned r = (v.u + 0x7FFF + ((v.u >> 16) & 1)) >> 16;
    return (unsigned short)r;
}
__device__ __forceinline__ float b2f(unsigned short h) {
    union { unsigned u; float f; } v; v.u = ((unsigned)h) << 16;
    return v.f;
}

// workspace float offsets
#define OFF_Q       0
#define OFF_KV      61440
#define OFF_QPT     184320
#define OFF_SHI     276480
#define OFF_SMID    337920
#define OFF_SLO     399360
#define OFF_ATTHI   552960
#define OFF_PARTG   552960
#define OFF_CCHI    2191360
#define OFF_BCAT    4074496
#define OFF_VKVHI   4997872
#define OFF_VKVLO   5120752
#define OFF_QPR     5243632
#define OFF_KVPR    5335792
#define OFF_GATE    5612272
#define OFF_KROW    6242032
#define OFF_WCTHI   6426352
#define OFF_WCTMID  6767344
#define OFF_WCTLO   7108336
#define OFF_WOTHI   7449328
#define OFF_WOTLO   7910128

// ---------------- kernel 0: fused cast s + bcat + weight split/transpose ---------
// bid < 487: s 3-way cast + bcat.  487..654: wc split+transpose.  else: wo.
__global__ __launch_bounds__(256) void k_prep(
    const float* __restrict__ s,
    const float* __restrict__ Wq, const float* __restrict__ bq,
    const float* __restrict__ Wkv, const float* __restrict__ bkv,
    const float* __restrict__ Wqp, const float* __restrict__ bqp,
    const float* __restrict__ Wkvp, const float* __restrict__ bkvp,
    const float* __restrict__ Wg, const float* __restrict__ bg,
    const float* __restrict__ Wo,
    unsigned short* __restrict__ s_hi, unsigned short* __restrict__ s_mid,
    unsigned short* __restrict__ s_lo, float* __restrict__ bcat,
    unsigned short* __restrict__ wcT_hi, unsigned short* __restrict__ wcT_mid,
    unsigned short* __restrict__ wcT_lo,
    unsigned short* __restrict__ woT_hi, unsigned short* __restrict__ woT_lo)
{
    __shared__ unsigned short th[64][65], tm[64][65], tl[64][65];
    int bid = blockIdx.x, tid = threadIdx.x;
    if (bid < 487) {
        int i = bid * 256 + tid;
        if (i < 122880) {
            float x = s[i];
            unsigned short hi = f2b(x);
            float r1 = x - b2f(hi);
            unsigned short mid = f2b(r1);
            s_hi[i] = hi; s_mid[i] = mid; s_lo[i] = f2b(r1 - b2f(mid));
            return;
        }
        i -= 122880;
        if (i < 1776) {
            float v;
            if (i < 192)       v = bq[i];
            else if (i < 576)  v = bkv[i - 192];
            else if (i < 864)  v = bqp[i - 576];
            else if (i < 1728) v = bkvp[i - 864];
            else               v = bg[i - 1728];
            bcat[i] = v;
        }
        return;
    }
    bid -= 487;
    if (bid < 168) {
        int k0 = (bid % 6) * 64, c0 = (bid / 6) * 64;
        #pragma unroll
        for (int rep = 0; rep < 16; rep++) {
            int idx = rep * 256 + tid;
            int i = idx >> 6, j = idx & 63;    // i = k-off, j = c-off
            int c = c0 + j, k = k0 + i;
            float v = 0.f;
            if (c < 1776) {
                if (c < 192)       v = Wq[(size_t)k * 192 + c];
                else if (c < 576)  v = Wkv[(size_t)k * 384 + c - 192];
                else if (c < 864)  v = Wqp[(size_t)k * 288 + c - 576];
                else if (c < 1728) v = Wkvp[(size_t)k * 864 + c - 864];
                else               v = Wg[(size_t)k * 48 + c - 1728];
            }
            unsigned short hi = f2b(v);
            float r1 = v - b2f(hi);
            unsigned short mid = f2b(r1);
            th[i][j] = hi; tm[i][j] = mid; tl[i][j] = f2b(r1 - b2f(mid));
        }
        __syncthreads();
        #pragma unroll
        for (int rep = 0; rep < 16; rep++) {
            int idx = rep * 256 + tid;
            int i = idx >> 6, j = idx & 63;    // i = c-off, j = k-off
            int c = c0 + i;
            if (c < 1776) {
                size_t o = (size_t)c * 384 + k0 + j;
                wcT_hi[o] = th[j][i]; wcT_mid[o] = tm[j][i]; wcT_lo[o] = tl[j][i];
            }
        }
    } else {
        int b = bid - 168;
        int r0 = (b % 38) * 64, c0 = (b / 38) * 64;
        #pragma unroll
        for (int rep = 0; rep < 16; rep++) {
            int idx = rep * 256 + tid;
            int i = idx >> 6, j = idx & 63;    // i = r-off, j = c-off
            int r = r0 + i;
            float v = 0.f;
            if (r < 2400) v = Wo[(size_t)r * 384 + c0 + j];
            unsigned short hi = f2b(v);
            th[i][j] = hi; tl[i][j] = f2b(v - b2f(hi));
        }
        __syncthreads();
        #pragma unroll
        for (int rep = 0; rep < 16; rep++) {
            int idx = rep * 256 + tid;
            int i = idx >> 6, j = idx & 63;    // i = c-off, j = r-off
            int r = r0 + j;
            if (r < 2400) {
                size_t o = (size_t)(c0 + i) * 2400 + r;
                woT_hi[o] = th[j][i]; woT_lo[o] = tl[j][i];
            }
        }
    }
}

// ---------------- kernel 1: projection GEMM, 3-way split MFMA, m=16 tiles ---------
__global__ __launch_bounds__(192) void k_proj(
    const unsigned short* __restrict__ s_hi, const unsigned short* __restrict__ s_mid,
    const unsigned short* __restrict__ s_lo,
    const unsigned short* __restrict__ wcT_hi, const unsigned short* __restrict__ wcT_mid,
    const unsigned short* __restrict__ wcT_lo,
    const float* __restrict__ bcat,
    float* __restrict__ qo, float* __restrict__ kvo,
    float* __restrict__ qpr, float* __restrict__ kvpr, float* __restrict__ gate)
{
    __shared__ unsigned short a_h[16][56], a_m[16][56], a_l[16][56];
    __shared__ unsigned short w_h[48][56], w_m[48][56], w_l[48][56];
    int col0 = blockIdx.x * 48, l0 = blockIdx.y * 16;
    int tid = threadIdx.x;
    int lane = tid & 63, w = tid >> 6;
    int ncol = lane & 15, blk = lane >> 4, mrow = (lane >> 4) * 4;

    float* dst; int nc, cbase; bool sig = false;
    if (col0 < 192)       { nc = 192; cbase = col0;        dst = qo;   }
    else if (col0 < 576)  { nc = 384; cbase = col0 - 192;  dst = kvo;  }
    else if (col0 < 864)  { nc = 288; cbase = col0 - 576;  dst = qpr;  }
    else if (col0 < 1728) { nc = 864; cbase = col0 - 864;  dst = kvpr; }
    else                  { nc = 48;  cbase = 0;           dst = gate; sig = true; }

    f32x4 acc = {};
    for (int k0 = 0; k0 < 384; k0 += 32) {
        __syncthreads();
        {
            int arr = tid >> 6, idx = tid & 63;
            int row = idx >> 2, seg = idx & 3;
            size_t off = (size_t)(l0 + row) * 384 + k0 + seg * 8;
            if (arr == 0)      *(short8*)&a_h[row][seg * 8] = *(const short8*)(s_hi + off);
            else if (arr == 1) *(short8*)&a_m[row][seg * 8] = *(const short8*)(s_mid + off);
            else               *(short8*)&a_l[row][seg * 8] = *(const short8*)(s_lo + off);
        }
        {
            int row = tid >> 2, seg = tid & 3;
            size_t off = (size_t)(col0 + row) * 384 + k0 + seg * 8;
            *(short8*)&w_h[row][seg * 8] = *(const short8*)(wcT_hi + off);
            *(short8*)&w_m[row][seg * 8] = *(const short8*)(wcT_mid + off);
            *(short8*)&w_l[row][seg * 8] = *(const short8*)(wcT_lo + off);
        }
        __syncthreads();
        short8 afh = *(short8*)&a_h[ncol][blk * 8];
        short8 afm = *(short8*)&a_m[ncol][blk * 8];
        short8 afl = *(short8*)&a_l[ncol][blk * 8];
        short8 bfh = *(short8*)&w_h[w * 16 + ncol][blk * 8];
        short8 bfm = *(short8*)&w_m[w * 16 + ncol][blk * 8];
        short8 bfl = *(short8*)&w_l[w * 16 + ncol][blk * 8];
        acc = __builtin_amdgcn_mfma_f32_16x16x32_bf16(afm, bfm, acc, 0, 0, 0);
        acc = __builtin_amdgcn_mfma_f32_16x16x32_bf16(afh, bfl, acc, 0, 0, 0);
        acc = __builtin_amdgcn_mfma_f32_16x16x32_bf16(afl, bfh, acc, 0, 0, 0);
        acc = __builtin_amdgcn_mfma_f32_16x16x32_bf16(afh, bfm, acc, 0, 0, 0);
        acc = __builtin_amdgcn_mfma_f32_16x16x32_bf16(afm, bfh, acc, 0, 0, 0);
        acc = __builtin_amdgcn_mfma_f32_16x16x32_bf16(afh, bfh, acc, 0, 0, 0);
    }
    {
        int n = w * 16 + ncol;
        float bv = bcat[col0 + n];
        int cloc = cbase + n;
        #pragma unroll
        for (int r = 0; r < 4; r++) {
            float v2 = acc[r] + bv;
            if (sig) v2 = 1.0f / (1.0f + expf(-v2));
            dst[(size_t)(l0 + mrow + r) * nc + cloc] = v2;
        }
    }
}

// ---------------- kernel 2: frame transforms + vkvT hi/lo + krow table ----------
__global__ __launch_bounds__(256) void k_points(
    const float* __restrict__ qpr, const float* __restrict__ kvpr, const float* __restrict__ gate,
    const float* __restrict__ rot, const float* __restrict__ trans,
    const float* __restrict__ kv,
    float* __restrict__ qpt, float* __restrict__ krow,
    unsigned short* __restrict__ vkv_hi, unsigned short* __restrict__ vkv_lo)
{
    __shared__ float vsh[96][6];
    __shared__ float kp_s[48][6];
    __shared__ float kn_s[48];
    int l = blockIdx.x, t = threadIdx.x;
    const float* R = rot + l * 9;
    float tx = trans[l * 3], ty = trans[l * 3 + 1], tz = trans[l * 3 + 2];
    if (t < 192) {
        const float* src; float g = 1.0f; float* dst = nullptr; int vj = -1, kj = -1;
        if (t < 48)      { src = qpr + (size_t)l * 288 + t * 6; g = gate[l * 48 + t]; dst = qpt + ((size_t)l * 48 + t) * 6; }
        else if (t < 96) { kj = t - 48; src = kvpr + (size_t)l * 864 + kj * 6; }
        else             { int j = t - 96; src = kvpr + (size_t)l * 864 + 288 + j * 6; vj = j; }
        float px = src[0], py = src[1], pz = src[2], ux = src[3], uy = src[4], uz = src[5];
        float c0 = R[0] * px + R[1] * py + R[2] * pz + tx;
        float c1 = R[3] * px + R[4] * py + R[5] * pz + ty;
        float c2 = R[6] * px + R[7] * py + R[8] * pz + tz;
        float d0 = R[0] * ux + R[1] * uy + R[2] * uz;
        float d1 = R[3] * ux + R[4] * uy + R[5] * uz;
        float d2 = R[6] * ux + R[7] * uy + R[8] * uz;
        if (vj >= 0) {
            vsh[vj][0] = c0; vsh[vj][1] = c1; vsh[vj][2] = c2;
            vsh[vj][3] = d0; vsh[vj][4] = d1; vsh[vj][5] = d2;
        } else if (kj >= 0) {
            kp_s[kj][0] = c0; kp_s[kj][1] = c1; kp_s[kj][2] = c2;
            kp_s[kj][3] = d0; kp_s[kj][4] = d1; kp_s[kj][5] = d2;
            kn_s[kj] = sqrtf(d0 * d0 + d1 * d1 + d2 * d2);
        } else {
            dst[0] = c0 * g; dst[1] = c1 * g; dst[2] = c2 * g;
            dst[3] = d0 * g; dst[4] = d1 * g; dst[5] = d2 * g;
        }
    }
    __syncthreads();
    #pragma unroll
    for (int e = 0; e < 3; e++) {
        int u = t * 3 + e;   // < 768
        int h = u >> 6, n = u & 63;
        float val;
        if (n < 16) val = kv[(size_t)l * 384 + 192 + h * 16 + n];
        else        val = vsh[h * 8 + (n - 16) / 6][(n - 16) % 6];
        unsigned short hi = f2b(val);
        size_t idx = ((size_t)h * 64 + n) * 320 + l;
        vkv_hi[idx] = hi;
        vkv_lo[idx] = f2b(val - b2f(hi));
    }
    for (int idx = t; idx < 576; idx += 256) {
        int h = idx / 48, j = idx - h * 48;
        float v;
        if (j < 24)      v = kp_s[h * 4 + j / 6][j % 6];
        else if (j < 40) v = kv[(size_t)l * 384 + h * 16 + (j - 24)];
        else if (j < 44) v = kn_s[h * 4 + (j - 40)];
        else             v = 0.0f;
        krow[((size_t)h * 320 + l) * 48 + j] = v;
    }
}

// ---------------- kernel 3: attention logits + softmax; krow staged in LDS -------
__global__ __launch_bounds__(256) void k_att(
    const float* __restrict__ qb, const float* __restrict__ qpt,
    const float* __restrict__ krow,
    const float* __restrict__ fm, const float* __restrict__ gw,
    const float* __restrict__ dwp, const float* __restrict__ hwp,
    float* __restrict__ att)
{
    __shared__ float ksh[320][45];   // 45-pad: stride 45 mod 32 = 13 -> phase-optimal b128
    int tid = threadIdx.x;
    int w = tid >> 6, lane = tid & 63;
    int iqA = blockIdx.x * 8 + w * 2;
    int iqB = iqA + 1;
    int h = blockIdx.y;

    // coalesced stage of krow[h] (only cols 0..44 kept)
    for (int idx = tid; idx < 320 * 48; idx += 256) {
        int kk = idx / 48, j = idx - kk * 48;
        if (j < 45) ksh[kk][j] = krow[((size_t)h * 320 + kk) * 48 + j];
    }

    float qvA[CH], qvB[CH];
    #pragma unroll
    for (int c = 0; c < CH; c++) {
        qvA[c] = qb[(size_t)iqA * 192 + h * CH + c];
        qvB[c] = qb[(size_t)iqB * 192 + h * CH + c];
    }
    float qpA[24], qpB[24];
    #pragma unroll
    for (int j = 0; j < 24; j++) {
        qpA[j] = qpt[(size_t)iqA * 288 + h * 24 + j];
        qpB[j] = qpt[(size_t)iqB * 288 + h * 24 + j];
    }
    float nqA[PQ], nq2A[PQ], nqB[PQ], nq2B[PQ];
    #pragma unroll
    for (int p = 0; p < PQ; p++) {
        float x = qpA[p * 6 + 3], y = qpA[p * 6 + 4], zz = qpA[p * 6 + 5];
        nq2A[p] = x * x + y * y + zz * zz; nqA[p] = sqrtf(nq2A[p]);
        x = qpB[p * 6 + 3]; y = qpB[p * 6 + 4]; zz = qpB[p * 6 + 5];
        nq2B[p] = x * x + y * y + zz * zz; nqB[p] = sqrtf(nq2B[p]);
    }
    float dwv = dwp[0], g0 = gw[0], g1 = gw[1], hwv = hwp[h];
    float fmA = fm[iqA], fmB = fm[iqB];
    __syncthreads();

    float lgA[5], lgB[5];
    for (int r = 0; r < 5; r++) {
        int kk = r * 64 + lane;
        const float* rowp = &ksh[kk][0];
        float rw[44];
        #pragma unroll
        for (int j = 0; j < 44; j++) rw[j] = rowp[j];
        float fmk = fm[kk];

        #pragma unroll
        for (int which = 0; which < 2; which++) {
            const float* qp = which ? qpB : qpA;
            const float* qv = which ? qvB : qvA;
            const float* nq = which ? nqB : nqA;
            const float* nq2 = which ? nq2B : nq2A;
            float fmi = which ? fmB : fmA;

            float scalar = 0.f;
            #pragma unroll
            for (int c = 0; c < CH; c++) scalar += qv[c] * rw[24 + c];
            scalar *= 0.25f;

            float pos = 0.f;
            #pragma unroll
            for (int p = 0; p < PQ; p++) {
                float dx = qp[p * 6] - rw[p * 6];
                float dy = qp[p * 6 + 1] - rw[p * 6 + 1];
                float dz = qp[p * 6 + 2] - rw[p * 6 + 2];
                float d = __builtin_amdgcn_sqrtf(dx * dx + dy * dy + dz * dz);
                float de = d + EPSF;
                pos += d + __logf(de) + __builtin_amdgcn_rcpf(de);
            }
            pos *= 0.25f;

            float dir = 0.f;
            #pragma unroll
            for (int p = 0; p < PQ; p++) {
                float kx = rw[p * 6 + 3], ky = rw[p * 6 + 4], kz = rw[p * 6 + 5];
                float nk = rw[40 + p];
                float nk2 = nk * nk;
                float cm = 0.f, dself = 0.f;
                #pragma unroll
                for (int pq = 0; pq < PQ; pq++) {
                    float dq = qp[pq * 6 + 3] * kx + qp[pq * 6 + 4] * ky + qp[pq * 6 + 5] * kz;
                    if (pq == p) dself = dq;
                    cm += __builtin_amdgcn_sqrtf(fmaxf(nq2[pq] * nk2 - dq * dq, 0.0f));
                }
                cm *= 0.25f;
                dir += dself - cm * __builtin_amdgcn_rcpf(nq[p] * nk + EPSF);
            }
            dir *= 0.25f;

            float logit = scalar + dwv * (g0 * pos + g1 * dir);
            logit *= hwv;
            logit += 100000.0f * (fmi * fmk - 1.0f);
            if (which) lgB[r] = logit; else lgA[r] = logit;
        }
    }

    // softmax A
    float mxA = lgA[0];
    #pragma unroll
    for (int r = 1; r < 5; r++) mxA = fmaxf(mxA, lgA[r]);
    for (int m = 32; m; m >>= 1) mxA = fmaxf(mxA, __shfl_xor(mxA, m, 64));
    float eA[5], smA = 0.f;
    #pragma unroll
    for (int r = 0; r < 5; r++) { eA[r] = __expf(lgA[r] - mxA); smA += eA[r]; }
    for (int m = 32; m; m >>= 1) smA += __shfl_xor(smA, m, 64);
    float invA = 1.0f / smA;
    #pragma unroll
    for (int r = 0; r < 5; r++)
        att[((size_t)h * 320 + iqA) * 320 + r * 64 + lane] = eA[r] * invA;
    // softmax B
    float mxB = lgB[0];
    #pragma unroll
    for (int r = 1; r < 5; r++) mxB = fmaxf(mxB, lgB[r]);
    for (int m = 32; m; m >>= 1) mxB = fmaxf(mxB, __shfl_xor(mxB, m, 64));
    float eB[5], smB = 0.f;
    #pragma unroll
    for (int r = 0; r < 5; r++) { eB[r] = __expf(lgB[r] - mxB); smB += eB[r]; }
    for (int m = 32; m; m >>= 1) smB += __shfl_xor(smB, m, 64);
    float invB = 1.0f / smB;
    #pragma unroll
    for (int r = 0; r < 5; r++)
        att[((size_t)h * 320 + iqB) * 320 + r * 64 + lane] = eB[r] * invB;
}

// ---------------- kernel 4: fused sv (bid<240) + pair (bid>=240) ----------------
__global__ __launch_bounds__(256) void k_svpair(
    const float* __restrict__ att,   // [12][320][320]
    const unsigned short* __restrict__ vkv_hi, const unsigned short* __restrict__ vkv_lo,
    const float* __restrict__ z,     // [320][320][128]
    const float* __restrict__ rot, const float* __restrict__ trans,
    float* __restrict__ cc)          // [320][2400]
{
    __shared__ unsigned short a_hi[16][56];
    __shared__ unsigned short a_lo[16][56];
    __shared__ unsigned short B[128][56];
    __shared__ float ogsh[16][49];
    int bid = blockIdx.x;
    int tid = threadIdx.x;
    int lane = tid & 63, w = tid >> 6;
    int ncol = lane & 15, blk = lane >> 4, mrow = (lane >> 4) * 4;

    if (bid < 240) {
        int iq0 = (bid % 20) * 16, h = bid / 20;
        f32x4 acc = {};
        for (int k0 = 0; k0 < 320; k0 += 32) {
            __syncthreads();
            {
                int row = tid >> 4, c2 = (tid & 15) * 2;
                const float* ap = att + ((size_t)h * 320 + iq0 + row) * 320 + k0 + c2;
                float v0 = ap[0], v1 = ap[1];
                ush2 h2, l2;
                h2[0] = f2b(v0); l2[0] = f2b(v0 - b2f(h2[0]));
                h2[1] = f2b(v1); l2[1] = f2b(v1 - b2f(h2[1]));
                *(ush2*)&a_hi[row][c2] = h2;
                *(ush2*)&a_lo[row][c2] = l2;
            }
            {
                int row = tid >> 2, seg = tid & 3;
                size_t off = ((size_t)h * 64 + row) * 320 + k0 + seg * 8;
                *(short8*)&B[row][seg * 8]      = *(const short8*)(vkv_hi + off);
                *(short8*)&B[64 + row][seg * 8] = *(const short8*)(vkv_lo + off);
            }
            __syncthreads();
            short8 afh = *(short8*)&a_hi[ncol][blk * 8];
            short8 afl = *(short8*)&a_lo[ncol][blk * 8];
            short8 bfh = *(short8*)&B[w * 16 + ncol][blk * 8];
            short8 bfl = *(short8*)&B[64 + w * 16 + ncol][blk * 8];
            acc = __builtin_amdgcn_mfma_f32_16x16x32_bf16(afh, bfh, acc, 0, 0, 0);
            acc = __builtin_amdgcn_mfma_f32_16x16x32_bf16(afh, bfl, acc, 0, 0, 0);
            acc = __builtin_amdgcn_mfma_f32_16x16x32_bf16(afl, bfh, acc, 0, 0, 0);
        }
        {
            int n = w * 16 + ncol;
            #pragma unroll
            for (int r = 0; r < 4; r++) {
                int iq = iq0 + mrow + r;
                float v = acc[r];
                if (n < 16) cc[(size_t)iq * 2400 + h * 16 + n] = v;
                else        ogsh[mrow + r][n - 16] = v;
            }
        }
        __syncthreads();
        if (tid < 128) {
            int iqr = tid >> 3, p = tid & 7;
            int l = iq0 + iqr;
            const float* R = rot + l * 9;
            float tx = trans[l * 3], ty = trans[l * 3 + 1], tz = trans[l * 3 + 2];
            const float* o = &ogsh[iqr][p * 6];
            float gx = o[0] - tx, gy = o[1] - ty, gz = o[2] - tz;
            float l0 = R[0] * gx + R[3] * gy + R[6] * gz;
            float l1 = R[1] * gx + R[4] * gy + R[7] * gz;
            float l2 = R[2] * gx + R[5] * gy + R[8] * gz;
            float dx = o[3], dy = o[4], dz = o[5];
            float e0 = R[0] * dx + R[3] * dy + R[6] * dz;
            float e1 = R[1] * dx + R[4] * dy + R[7] * dz;
            float e2 = R[2] * dx + R[5] * dy + R[8] * dz;
            float n = sqrtf(e0 * e0 + e1 * e1 + e2 * e2);
            float inv = 1.0f / fmaxf(n, 1e-12f);
            float ln = sqrtf(l0 * l0 + l1 * l1 + l2 * l2);
            float vals[7] = { l0, l1, l2, e0 * inv, e1 * inv, e2 * inv, ln };
            size_t base = (size_t)l * 2400 + 192 + (h * PV + p) * 7;
            #pragma unroll
            for (int j = 0; j < 7; j++) cc[base + j] = vals[j];
        }
    } else {
        int iq = bid - 240;
        int kp2 = (tid & 15) * 2;
        int cb = (tid >> 4) * 8;
        const float* zbase = z + ((size_t)iq * 320 + kp2) * 128 + cb;

        float4 zA0, zA1, zA2, zA3, zB0, zB1, zB2, zB3;
        {
            const float* p = zbase;
            zA0 = *(const float4*)(p);       zA1 = *(const float4*)(p + 4);
            zA2 = *(const float4*)(p + 128); zA3 = *(const float4*)(p + 132);
            p = zbase + (size_t)32 * 128;
            zB0 = *(const float4*)(p);       zB1 = *(const float4*)(p + 4);
            zB2 = *(const float4*)(p + 128); zB3 = *(const float4*)(p + 132);
        }

        f32x4 acc[2] = {};
        #pragma unroll
        for (int i = 0; i < 10; i++) {
            int k0 = i * 32;
            __syncthreads();
            {
                int row = tid >> 4, c2 = (tid & 15) * 2;
                float v0 = 0.f, v1 = 0.f;
                if (row < 12) {
                    const float* ap = att + ((size_t)row * 320 + iq) * 320 + k0 + c2;
                    v0 = ap[0]; v1 = ap[1];
                }
                ush2 h2, l2;
                h2[0] = f2b(v0); l2[0] = f2b(v0 - b2f(h2[0]));
                h2[1] = f2b(v1); l2[1] = f2b(v1 - b2f(h2[1]));
                *(ush2*)&a_hi[row][c2] = h2;
                *(ush2*)&a_lo[row][c2] = l2;
            }
            {
                float va[8], vb[8];
                if ((i & 1) == 0) {
                    va[0]=zA0.x; va[1]=zA0.y; va[2]=zA0.z; va[3]=zA0.w;
                    va[4]=zA1.x; va[5]=zA1.y; va[6]=zA1.z; va[7]=zA1.w;
                    vb[0]=zA2.x; vb[1]=zA2.y; vb[2]=zA2.z; vb[3]=zA2.w;
                    vb[4]=zA3.x; vb[5]=zA3.y; vb[6]=zA3.z; vb[7]=zA3.w;
                } else {
                    va[0]=zB0.x; va[1]=zB0.y; va[2]=zB0.z; va[3]=zB0.w;
                    va[4]=zB1.x; va[5]=zB1.y; va[6]=zB1.z; va[7]=zB1.w;
                    vb[0]=zB2.x; vb[1]=zB2.y; vb[2]=zB2.z; vb[3]=zB2.w;
                    vb[4]=zB3.x; vb[5]=zB3.y; vb[6]=zB3.z; vb[7]=zB3.w;
                }
                #pragma unroll
                for (int c = 0; c < 8; c++) {
                    ush2 pr;
                    pr[0] = f2b(va[c]);
                    pr[1] = f2b(vb[c]);
                    *(ush2*)&B[cb + c][kp2] = pr;
                }
                if (i + 2 < 10) {
                    const float* p = zbase + (size_t)(k0 + 64) * 128;
                    if ((i & 1) == 0) {
                        zA0 = *(const float4*)(p);       zA1 = *(const float4*)(p + 4);
                        zA2 = *(const float4*)(p + 128); zA3 = *(const float4*)(p + 132);
                    } else {
                        zB0 = *(const float4*)(p);       zB1 = *(const float4*)(p + 4);
                        zB2 = *(const float4*)(p + 128); zB3 = *(const float4*)(p + 132);
                    }
                }
            }
            __syncthreads();
            short8 afh = *(short8*)&a_hi[ncol][blk * 8];
            short8 afl = *(short8*)&a_lo[ncol][blk * 8];
            #pragma unroll
            for (int s2 = 0; s2 < 2; s2++) {
                short8 bf = *(short8*)&B[w * 32 + s2 * 16 + ncol][blk * 8];
                acc[s2] = __builtin_amdgcn_mfma_f32_16x16x32_bf16(afl, bf, acc[s2], 0, 0, 0);
                acc[s2] = __builtin_amdgcn_mfma_f32_16x16x32_bf16(afh, bf, acc[s2], 0, 0, 0);
            }
        }
        #pragma unroll
        for (int s2 = 0; s2 < 2; s2++) {
            int n = w * 32 + s2 * 16 + ncol;
            #pragma unroll
            for (int r = 0; r < 4; r++) {
                int h = mrow + r;
                if (h < 12)
                    cc[(size_t)iq * 2400 + 864 + (size_t)h * 128 + n] = acc[s2][r];
            }
        }
    }
}

// ---------------- kernel 5: partials = cc @ Wo; A split in-kernel ----------------
__global__ __launch_bounds__(256) void k_gemm(
    const float* __restrict__ cc,
    const unsigned short* __restrict__ woT_hi, const unsigned short* __restrict__ woT_lo,
    float* __restrict__ part)
{
    __shared__ unsigned short a_h[16][56], a_l[16][56];
    __shared__ unsigned short w_h[64][56], w_l[64][56];
    int iq0 = blockIdx.x * 16, col0 = blockIdx.y * 64, ks = blockIdx.z;
    int tid = threadIdx.x;
    int lane = tid & 63, w = tid >> 6;
    int ncol = lane & 15, blk = lane >> 4, mrow = (lane >> 4) * 4;

    f32x4 acc = {};
    for (int kc = 0; kc < 15; kc++) {
        int k0 = ks * 480 + kc * 32;
        __syncthreads();
        {
            int row = tid >> 4, c2 = (tid & 15) * 2;
            const float* ap = cc + (size_t)(iq0 + row) * 2400 + k0 + c2;
            float v0 = ap[0], v1 = ap[1];
            ush2 h2, l2;
            h2[0] = f2b(v0); l2[0] = f2b(v0 - b2f(h2[0]));
            h2[1] = f2b(v1); l2[1] = f2b(v1 - b2f(h2[1]));
            *(ush2*)&a_h[row][c2] = h2;
            *(ush2*)&a_l[row][c2] = l2;
        }
        #pragma unroll
        for (int t2 = 0; t2 < 2; t2++) {
            int idx = tid * 2 + t2;          // 0..511
            int arr = idx >> 8, i2 = idx & 255;
            int row = i2 >> 2, seg = i2 & 3;
            size_t off = (size_t)(col0 + row) * 2400 + k0 + seg * 8;
            if (arr == 0) *(short8*)&w_h[row][seg * 8] = *(const short8*)(woT_hi + off);
            else          *(short8*)&w_l[row][seg * 8] = *(const short8*)(woT_lo + off);
        }
        __syncthreads();
        short8 afh = *(short8*)&a_h[ncol][blk * 8];
        short8 afl = *(short8*)&a_l[ncol][blk * 8];
        short8 bfh = *(short8*)&w_h[w * 16 + ncol][blk * 8];
        short8 bfl = *(short8*)&w_l[w * 16 + ncol][blk * 8];
        acc = __builtin_amdgcn_mfma_f32_16x16x32_bf16(afh, bfh, acc, 0, 0, 0);
        acc = __builtin_amdgcn_mfma_f32_16x16x32_bf16(afh, bfl, acc, 0, 0, 0);
        acc = __builtin_amdgcn_mfma_f32_16x16x32_bf16(afl, bfh, acc, 0, 0, 0);
    }
    {
        int cn = col0 + w * 16 + ncol;
        #pragma unroll
        for (int r = 0; r < 4; r++)
            part[((size_t)ks * 320 + iq0 + mrow + r) * 384 + cn] = acc[r];
    }
}

// ---------------- kernel 6: out = bo + sum of 5 partials (deterministic) ----------
__global__ __launch_bounds__(256) void k_reduce(
    const float* __restrict__ part, const float* __restrict__ bo, float* __restrict__ out)
{
    int i = blockIdx.x * 256 + threadIdx.x;   // < 122880
    float v = bo[i % CS];
    #pragma unroll
    for (int ks = 0; ks < 5; ks++) v += part[(size_t)ks * 122880 + i];
    out[i] = v;
}

extern "C" void kernel_launch(void* const* d_in, const int* in_sizes, int n_in,
                              void* d_out, int out_size, void* d_ws, size_t ws_size,
                              hipStream_t stream)
{
    const float* s     = (const float*)d_in[0];
    const float* rot   = (const float*)d_in[1];
    const float* trans = (const float*)d_in[2];
    const float* z     = (const float*)d_in[3];
    const float* fm    = (const float*)d_in[4];
    const float* Wq    = (const float*)d_in[5];
    const float* bq    = (const float*)d_in[6];
    const float* Wkv   = (const float*)d_in[7];
    const float* bkv   = (const float*)d_in[8];
    const float* Wqp   = (const float*)d_in[9];
    const float* bqp   = (const float*)d_in[10];
    const float* Wkvp  = (const float*)d_in[11];
    const float* bkvp  = (const float*)d_in[12];
    const float* Wg    = (const float*)d_in[13];
    const float* bg    = (const float*)d_in[14];
    const float* gw    = (const float*)d_in[15];
    const float* dw    = (const float*)d_in[16];
    const float* hw    = (const float*)d_in[17];
    const float* Wo    = (const float*)d_in[18];
    const float* bo    = (const float*)d_in[19];

    float* ws = (float*)d_ws;
    float*          q       = ws + OFF_Q;
    float*          kv      = ws + OFF_KV;
    float*          qpt     = ws + OFF_QPT;
    float*          att     = ws + OFF_ATTHI;
    float*          part    = ws + OFF_PARTG;
    float*          cc      = ws + OFF_CCHI;
    unsigned short* s_hi    = (unsigned short*)(ws + OFF_SHI);
    unsigned short* s_mid   = (unsigned short*)(ws + OFF_SMID);
    unsigned short* s_lo    = (unsigned short*)(ws + OFF_SLO);
    float*          bcat    = ws + OFF_BCAT;
    unsigned short* vkv_hi  = (unsigned short*)(ws + OFF_VKVHI);
    unsigned short* vkv_lo  = (unsigned short*)(ws + OFF_VKVLO);
    float*          qpr     = ws + OFF_QPR;
    float*          kvpr    = ws + OFF_KVPR;
    float*          gate    = ws + OFF_GATE;
    float*          krow    = ws + OFF_KROW;
    unsigned short* wcT_hi  = (unsigned short*)(ws + OFF_WCTHI);
    unsigned short* wcT_mid = (unsigned short*)(ws + OFF_WCTMID);
    unsigned short* wcT_lo  = (unsigned short*)(ws + OFF_WCTLO);
    unsigned short* woT_hi  = (unsigned short*)(ws + OFF_WOTHI);
    unsigned short* woT_lo  = (unsigned short*)(ws + OFF_WOTLO);
    float* out = (float*)d_out;

    k_prep<<<dim3(883), dim3(256), 0, stream>>>(s, Wq, bq, Wkv, bkv, Wqp, bqp,
                                                Wkvp, bkvp, Wg, bg, Wo,
                                                s_hi, s_mid, s_lo, bcat,
                                                wcT_hi, wcT_mid, wcT_lo, woT_hi, woT_lo);
    k_proj<<<dim3(37, 20), dim3(192), 0, stream>>>(s_hi, s_mid, s_lo, wcT_hi, wcT_mid, wcT_lo,
                                                   bcat, q, kv, qpr, kvpr, gate);
    k_points<<<dim3(LSEQ), dim3(256), 0, stream>>>(qpr, kvpr, gate, rot, trans, kv,
                                                   qpt, krow, vkv_hi, vkv_lo);
    k_att<<<dim3(40, NH), dim3(256), 0, stream>>>(q, qpt, krow, fm, gw, dw, hw, att);
    k_svpair<<<dim3(560), dim3(256), 0, stream>>>(att, vkv_hi, vkv_lo, z, rot, trans, cc);
    k_gemm<<<dim3(20, 6, 5), dim3(256), 0, stream>>>(cc, woT_hi, woT_lo, part);
    k_reduce<<<dim3(480), dim3(256), 0, stream>>>(part, bo, out);
}

// Round 9
// 208.346 us; speedup vs baseline: 1.0848x; 1.0848x over previous
//
#include <hip/hip_runtime.h>
#include <hip/hip_bf16.h>
#include <math.h>

#define LSEQ 320
#define CS 384
#define CZ 128
#define CH 16
#define NH 12
#define PQ 4
#define PV 8
#define EPSF 1e-8f

typedef short short8 __attribute__((ext_vector_type(8)));
typedef float f32x4 __attribute__((ext_vector_type(4)));
typedef unsigned short ush2 __attribute__((ext_vector_type(2)));

// float -> bf16 (RNE)
__device__ __forceinline__ unsigned short f2b(float x) {
    union { float f; unsigned u; } v; v.f = x;
    unsigned r = (v.u + 0x7FFF + ((v.u >> 16) & 1)) >> 16;
    return (unsigned short)r;
}
__device__ __forceinline__ float b2f(unsigned short h) {
    union { unsigned u; float f; } v; v.u = ((unsigned)h) << 16;
    return v.f;
}

// workspace float offsets
#define OFF_Q       0
#define OFF_KV      61440
#define OFF_QPT     184320
#define OFF_SHI     276480
#define OFF_SMID    337920
#define OFF_SLO     399360
#define OFF_ATTHI   552960
#define OFF_PARTG   552960
#define OFF_CCHI    2191360
#define OFF_BCAT    4074496
#define OFF_VKVHI   4997872
#define OFF_VKVLO   5120752
#define OFF_QPR     5243632
#define OFF_KVPR    5335792
#define OFF_GATE    5612272
#define OFF_KROW    6242032
#define OFF_WCTHI   6426352
#define OFF_WCTMID  6767344
#define OFF_WCTLO   7108336
#define OFF_WOTHI   7449328
#define OFF_WOTLO   7910128

// ---------------- kernel 0: fused cast s + bcat + weight split/transpose ---------
// bid < 487: s 3-way cast + bcat.  487..654: wc split+transpose.  else: wo.
__global__ __launch_bounds__(256) void k_prep(
    const float* __restrict__ s,
    const float* __restrict__ Wq, const float* __restrict__ bq,
    const float* __restrict__ Wkv, const float* __restrict__ bkv,
    const float* __restrict__ Wqp, const float* __restrict__ bqp,
    const float* __restrict__ Wkvp, const float* __restrict__ bkvp,
    const float* __restrict__ Wg, const float* __restrict__ bg,
    const float* __restrict__ Wo,
    unsigned short* __restrict__ s_hi, unsigned short* __restrict__ s_mid,
    unsigned short* __restrict__ s_lo, float* __restrict__ bcat,
    unsigned short* __restrict__ wcT_hi, unsigned short* __restrict__ wcT_mid,
    unsigned short* __restrict__ wcT_lo,
    unsigned short* __restrict__ woT_hi, unsigned short* __restrict__ woT_lo)
{
    __shared__ unsigned short th[64][65], tm[64][65], tl[64][65];
    int bid = blockIdx.x, tid = threadIdx.x;
    if (bid < 487) {
        int i = bid * 256 + tid;
        if (i < 122880) {
            float x = s[i];
            unsigned short hi = f2b(x);
            float r1 = x - b2f(hi);
            unsigned short mid = f2b(r1);
            s_hi[i] = hi; s_mid[i] = mid; s_lo[i] = f2b(r1 - b2f(mid));
            return;
        }
        i -= 122880;
        if (i < 1776) {
            float v;
            if (i < 192)       v = bq[i];
            else if (i < 576)  v = bkv[i - 192];
            else if (i < 864)  v = bqp[i - 576];
            else if (i < 1728) v = bkvp[i - 864];
            else               v = bg[i - 1728];
            bcat[i] = v;
        }
        return;
    }
    bid -= 487;
    if (bid < 168) {
        int k0 = (bid % 6) * 64, c0 = (bid / 6) * 64;
        #pragma unroll
        for (int rep = 0; rep < 16; rep++) {
            int idx = rep * 256 + tid;
            int i = idx >> 6, j = idx & 63;    // i = k-off, j = c-off
            int c = c0 + j, k = k0 + i;
            float v = 0.f;
            if (c < 1776) {
                if (c < 192)       v = Wq[(size_t)k * 192 + c];
                else if (c < 576)  v = Wkv[(size_t)k * 384 + c - 192];
                else if (c < 864)  v = Wqp[(size_t)k * 288 + c - 576];
                else if (c < 1728) v = Wkvp[(size_t)k * 864 + c - 864];
                else               v = Wg[(size_t)k * 48 + c - 1728];
            }
            unsigned short hi = f2b(v);
            float r1 = v - b2f(hi);
            unsigned short mid = f2b(r1);
            th[i][j] = hi; tm[i][j] = mid; tl[i][j] = f2b(r1 - b2f(mid));
        }
        __syncthreads();
        #pragma unroll
        for (int rep = 0; rep < 16; rep++) {
            int idx = rep * 256 + tid;
            int i = idx >> 6, j = idx & 63;    // i = c-off, j = k-off
            int c = c0 + i;
            if (c < 1776) {
                size_t o = (size_t)c * 384 + k0 + j;
                wcT_hi[o] = th[j][i]; wcT_mid[o] = tm[j][i]; wcT_lo[o] = tl[j][i];
            }
        }
    } else {
        int b = bid - 168;
        int r0 = (b % 38) * 64, c0 = (b / 38) * 64;
        #pragma unroll
        for (int rep = 0; rep < 16; rep++) {
            int idx = rep * 256 + tid;
            int i = idx >> 6, j = idx & 63;    // i = r-off, j = c-off
            int r = r0 + i;
            float v = 0.f;
            if (r < 2400) v = Wo[(size_t)r * 384 + c0 + j];
            unsigned short hi = f2b(v);
            th[i][j] = hi; tl[i][j] = f2b(v - b2f(hi));
        }
        __syncthreads();
        #pragma unroll
        for (int rep = 0; rep < 16; rep++) {
            int idx = rep * 256 + tid;
            int i = idx >> 6, j = idx & 63;    // i = c-off, j = r-off
            int r = r0 + j;
            if (r < 2400) {
                size_t o = (size_t)(c0 + i) * 2400 + r;
                woT_hi[o] = th[j][i]; woT_lo[o] = tl[j][i];
            }
        }
    }
}

// ---------------- kernel 1: projection GEMM, 3-way split MFMA, m=16 tiles ---------
__global__ __launch_bounds__(192) void k_proj(
    const unsigned short* __restrict__ s_hi, const unsigned short* __restrict__ s_mid,
    const unsigned short* __restrict__ s_lo,
    const unsigned short* __restrict__ wcT_hi, const unsigned short* __restrict__ wcT_mid,
    const unsigned short* __restrict__ wcT_lo,
    const float* __restrict__ bcat,
    float* __restrict__ qo, float* __restrict__ kvo,
    float* __restrict__ qpr, float* __restrict__ kvpr, float* __restrict__ gate)
{
    __shared__ unsigned short a_h[16][56], a_m[16][56], a_l[16][56];
    __shared__ unsigned short w_h[48][56], w_m[48][56], w_l[48][56];
    int col0 = blockIdx.x * 48, l0 = blockIdx.y * 16;
    int tid = threadIdx.x;
    int lane = tid & 63, w = tid >> 6;
    int ncol = lane & 15, blk = lane >> 4, mrow = (lane >> 4) * 4;

    float* dst; int nc, cbase; bool sig = false;
    if (col0 < 192)       { nc = 192; cbase = col0;        dst = qo;   }
    else if (col0 < 576)  { nc = 384; cbase = col0 - 192;  dst = kvo;  }
    else if (col0 < 864)  { nc = 288; cbase = col0 - 576;  dst = qpr;  }
    else if (col0 < 1728) { nc = 864; cbase = col0 - 864;  dst = kvpr; }
    else                  { nc = 48;  cbase = 0;           dst = gate; sig = true; }

    f32x4 acc = {};
    for (int k0 = 0; k0 < 384; k0 += 32) {
        __syncthreads();
        {
            int arr = tid >> 6, idx = tid & 63;
            int row = idx >> 2, seg = idx & 3;
            size_t off = (size_t)(l0 + row) * 384 + k0 + seg * 8;
            if (arr == 0)      *(short8*)&a_h[row][seg * 8] = *(const short8*)(s_hi + off);
            else if (arr == 1) *(short8*)&a_m[row][seg * 8] = *(const short8*)(s_mid + off);
            else               *(short8*)&a_l[row][seg * 8] = *(const short8*)(s_lo + off);
        }
        {
            int row = tid >> 2, seg = tid & 3;
            size_t off = (size_t)(col0 + row) * 384 + k0 + seg * 8;
            *(short8*)&w_h[row][seg * 8] = *(const short8*)(wcT_hi + off);
            *(short8*)&w_m[row][seg * 8] = *(const short8*)(wcT_mid + off);
            *(short8*)&w_l[row][seg * 8] = *(const short8*)(wcT_lo + off);
        }
        __syncthreads();
        short8 afh = *(short8*)&a_h[ncol][blk * 8];
        short8 afm = *(short8*)&a_m[ncol][blk * 8];
        short8 afl = *(short8*)&a_l[ncol][blk * 8];
        short8 bfh = *(short8*)&w_h[w * 16 + ncol][blk * 8];
        short8 bfm = *(short8*)&w_m[w * 16 + ncol][blk * 8];
        short8 bfl = *(short8*)&w_l[w * 16 + ncol][blk * 8];
        acc = __builtin_amdgcn_mfma_f32_16x16x32_bf16(afm, bfm, acc, 0, 0, 0);
        acc = __builtin_amdgcn_mfma_f32_16x16x32_bf16(afh, bfl, acc, 0, 0, 0);
        acc = __builtin_amdgcn_mfma_f32_16x16x32_bf16(afl, bfh, acc, 0, 0, 0);
        acc = __builtin_amdgcn_mfma_f32_16x16x32_bf16(afh, bfm, acc, 0, 0, 0);
        acc = __builtin_amdgcn_mfma_f32_16x16x32_bf16(afm, bfh, acc, 0, 0, 0);
        acc = __builtin_amdgcn_mfma_f32_16x16x32_bf16(afh, bfh, acc, 0, 0, 0);
    }
    {
        int n = w * 16 + ncol;
        float bv = bcat[col0 + n];
        int cloc = cbase + n;
        #pragma unroll
        for (int r = 0; r < 4; r++) {
            float v2 = acc[r] + bv;
            if (sig) v2 = 1.0f / (1.0f + expf(-v2));
            dst[(size_t)(l0 + mrow + r) * nc + cloc] = v2;
        }
    }
}

// ---------------- kernel 2: frame transforms + vkvT hi/lo + krow table ----------
__global__ __launch_bounds__(256) void k_points(
    const float* __restrict__ qpr, const float* __restrict__ kvpr, const float* __restrict__ gate,
    const float* __restrict__ rot, const float* __restrict__ trans,
    const float* __restrict__ kv,
    float* __restrict__ qpt, float* __restrict__ krow,
    unsigned short* __restrict__ vkv_hi, unsigned short* __restrict__ vkv_lo)
{
    __shared__ float vsh[96][6];
    __shared__ float kp_s[48][6];
    __shared__ float kn_s[48];
    int l = blockIdx.x, t = threadIdx.x;
    const float* R = rot + l * 9;
    float tx = trans[l * 3], ty = trans[l * 3 + 1], tz = trans[l * 3 + 2];
    if (t < 192) {
        const float* src; float g = 1.0f; float* dst = nullptr; int vj = -1, kj = -1;
        if (t < 48)      { src = qpr + (size_t)l * 288 + t * 6; g = gate[l * 48 + t]; dst = qpt + ((size_t)l * 48 + t) * 6; }
        else if (t < 96) { kj = t - 48; src = kvpr + (size_t)l * 864 + kj * 6; }
        else             { int j = t - 96; src = kvpr + (size_t)l * 864 + 288 + j * 6; vj = j; }
        float px = src[0], py = src[1], pz = src[2], ux = src[3], uy = src[4], uz = src[5];
        float c0 = R[0] * px + R[1] * py + R[2] * pz + tx;
        float c1 = R[3] * px + R[4] * py + R[5] * pz + ty;
        float c2 = R[6] * px + R[7] * py + R[8] * pz + tz;
        float d0 = R[0] * ux + R[1] * uy + R[2] * uz;
        float d1 = R[3] * ux + R[4] * uy + R[5] * uz;
        float d2 = R[6] * ux + R[7] * uy + R[8] * uz;
        if (vj >= 0) {
            vsh[vj][0] = c0; vsh[vj][1] = c1; vsh[vj][2] = c2;
            vsh[vj][3] = d0; vsh[vj][4] = d1; vsh[vj][5] = d2;
        } else if (kj >= 0) {
            kp_s[kj][0] = c0; kp_s[kj][1] = c1; kp_s[kj][2] = c2;
            kp_s[kj][3] = d0; kp_s[kj][4] = d1; kp_s[kj][5] = d2;
            kn_s[kj] = sqrtf(d0 * d0 + d1 * d1 + d2 * d2);
        } else {
            dst[0] = c0 * g; dst[1] = c1 * g; dst[2] = c2 * g;
            dst[3] = d0 * g; dst[4] = d1 * g; dst[5] = d2 * g;
        }
    }
    __syncthreads();
    #pragma unroll
    for (int e = 0; e < 3; e++) {
        int u = t * 3 + e;   // < 768
        int h = u >> 6, n = u & 63;
        float val;
        if (n < 16) val = kv[(size_t)l * 384 + 192 + h * 16 + n];
        else        val = vsh[h * 8 + (n - 16) / 6][(n - 16) % 6];
        unsigned short hi = f2b(val);
        size_t idx = ((size_t)h * 64 + n) * 320 + l;
        vkv_hi[idx] = hi;
        vkv_lo[idx] = f2b(val - b2f(hi));
    }
    for (int idx = t; idx < 576; idx += 256) {
        int h = idx / 48, j = idx - h * 48;
        float v;
        if (j < 24)      v = kp_s[h * 4 + j / 6][j % 6];
        else if (j < 40) v = kv[(size_t)l * 384 + h * 16 + (j - 24)];
        else if (j < 44) v = kn_s[h * 4 + (j - 40)];
        else             v = 0.0f;
        krow[((size_t)h * 320 + l) * 48 + j] = v;
    }
}

// ---------------- kernel 3: attention logits + softmax, 2 iq per wave -------------
__global__ __launch_bounds__(256) void k_att(
    const float* __restrict__ qb, const float* __restrict__ qpt,
    const float* __restrict__ krow,
    const float* __restrict__ fm, const float* __restrict__ gw,
    const float* __restrict__ dwp, const float* __restrict__ hwp,
    float* __restrict__ att)
{
    int tid = threadIdx.x;
    int w = tid >> 6, lane = tid & 63;
    int iqA = blockIdx.x * 8 + w * 2;
    int iqB = iqA + 1;
    int h = blockIdx.y;

    float qvA[CH], qvB[CH];
    #pragma unroll
    for (int c = 0; c < CH; c++) {
        qvA[c] = qb[(size_t)iqA * 192 + h * CH + c];
        qvB[c] = qb[(size_t)iqB * 192 + h * CH + c];
    }
    float qpA[24], qpB[24];
    #pragma unroll
    for (int j = 0; j < 24; j++) {
        qpA[j] = qpt[(size_t)iqA * 288 + h * 24 + j];
        qpB[j] = qpt[(size_t)iqB * 288 + h * 24 + j];
    }
    float nqA[PQ], nq2A[PQ], nqB[PQ], nq2B[PQ];
    #pragma unroll
    for (int p = 0; p < PQ; p++) {
        float x = qpA[p * 6 + 3], y = qpA[p * 6 + 4], zz = qpA[p * 6 + 5];
        nq2A[p] = x * x + y * y + zz * zz; nqA[p] = sqrtf(nq2A[p]);
        x = qpB[p * 6 + 3]; y = qpB[p * 6 + 4]; zz = qpB[p * 6 + 5];
        nq2B[p] = x * x + y * y + zz * zz; nqB[p] = sqrtf(nq2B[p]);
    }
    float dwv = dwp[0], g0 = gw[0], g1 = gw[1], hwv = hwp[h];
    float fmA = fm[iqA], fmB = fm[iqB];

    float lgA[5], lgB[5];
    for (int r = 0; r < 5; r++) {
        int kk = r * 64 + lane;
        const float* rowp = krow + ((size_t)h * 320 + kk) * 48;
        float rw[44];
        #pragma unroll
        for (int j = 0; j < 44; j++) rw[j] = rowp[j];
        float fmk = fm[kk];

        #pragma unroll
        for (int which = 0; which < 2; which++) {
            const float* qp = which ? qpB : qpA;
            const float* qv = which ? qvB : qvA;
            const float* nq = which ? nqB : nqA;
            const float* nq2 = which ? nq2B : nq2A;
            float fmi = which ? fmB : fmA;

            float scalar = 0.f;
            #pragma unroll
            for (int c = 0; c < CH; c++) scalar += qv[c] * rw[24 + c];
            scalar *= 0.25f;

            float pos = 0.f;
            #pragma unroll
            for (int p = 0; p < PQ; p++) {
                float dx = qp[p * 6] - rw[p * 6];
                float dy = qp[p * 6 + 1] - rw[p * 6 + 1];
                float dz = qp[p * 6 + 2] - rw[p * 6 + 2];
                float d = __builtin_amdgcn_sqrtf(dx * dx + dy * dy + dz * dz);
                float de = d + EPSF;
                pos += d + __logf(de) + __builtin_amdgcn_rcpf(de);
            }
            pos *= 0.25f;

            float dir = 0.f;
            #pragma unroll
            for (int p = 0; p < PQ; p++) {
                float kx = rw[p * 6 + 3], ky = rw[p * 6 + 4], kz = rw[p * 6 + 5];
                float nk = rw[40 + p];
                float nk2 = nk * nk;
                float cm = 0.f, dself = 0.f;
                #pragma unroll
                for (int pq = 0; pq < PQ; pq++) {
                    float dq = qp[pq * 6 + 3] * kx + qp[pq * 6 + 4] * ky + qp[pq * 6 + 5] * kz;
                    if (pq == p) dself = dq;
                    cm += __builtin_amdgcn_sqrtf(fmaxf(nq2[pq] * nk2 - dq * dq, 0.0f));
                }
                cm *= 0.25f;
                dir += dself - cm * __builtin_amdgcn_rcpf(nq[p] * nk + EPSF);
            }
            dir *= 0.25f;

            float logit = scalar + dwv * (g0 * pos + g1 * dir);
            logit *= hwv;
            logit += 100000.0f * (fmi * fmk - 1.0f);
            if (which) lgB[r] = logit; else lgA[r] = logit;
        }
    }

    // softmax A
    float mxA = lgA[0];
    #pragma unroll
    for (int r = 1; r < 5; r++) mxA = fmaxf(mxA, lgA[r]);
    for (int m = 32; m; m >>= 1) mxA = fmaxf(mxA, __shfl_xor(mxA, m, 64));
    float eA[5], smA = 0.f;
    #pragma unroll
    for (int r = 0; r < 5; r++) { eA[r] = __expf(lgA[r] - mxA); smA += eA[r]; }
    for (int m = 32; m; m >>= 1) smA += __shfl_xor(smA, m, 64);
    float invA = 1.0f / smA;
    #pragma unroll
    for (int r = 0; r < 5; r++)
        att[((size_t)h * 320 + iqA) * 320 + r * 64 + lane] = eA[r] * invA;
    // softmax B
    float mxB = lgB[0];
    #pragma unroll
    for (int r = 1; r < 5; r++) mxB = fmaxf(mxB, lgB[r]);
    for (int m = 32; m; m >>= 1) mxB = fmaxf(mxB, __shfl_xor(mxB, m, 64));
    float eB[5], smB = 0.f;
    #pragma unroll
    for (int r = 0; r < 5; r++) { eB[r] = __expf(lgB[r] - mxB); smB += eB[r]; }
    for (int m = 32; m; m >>= 1) smB += __shfl_xor(smB, m, 64);
    float invB = 1.0f / smB;
    #pragma unroll
    for (int r = 0; r < 5; r++)
        att[((size_t)h * 320 + iqB) * 320 + r * 64 + lane] = eB[r] * invB;
}

// ---------------- kernel 4: fused sv (bid<240) + pair (bid>=240) ----------------
__global__ __launch_bounds__(256) void k_svpair(
    const float* __restrict__ att,   // [12][320][320]
    const unsigned short* __restrict__ vkv_hi, const unsigned short* __restrict__ vkv_lo,
    const float* __restrict__ z,     // [320][320][128]
    const float* __restrict__ rot, const float* __restrict__ trans,
    float* __restrict__ cc)          // [320][2400]
{
    __shared__ unsigned short a_hi[16][56];
    __shared__ unsigned short a_lo[16][56];
    __shared__ unsigned short B[128][56];
    __shared__ float ogsh[16][49];
    int bid = blockIdx.x;
    int tid = threadIdx.x;
    int lane = tid & 63, w = tid >> 6;
    int ncol = lane & 15, blk = lane >> 4, mrow = (lane >> 4) * 4;

    if (bid < 240) {
        int iq0 = (bid % 20) * 16, h = bid / 20;
        f32x4 acc = {};
        for (int k0 = 0; k0 < 320; k0 += 32) {
            __syncthreads();
            {
                int row = tid >> 4, c2 = (tid & 15) * 2;
                const float* ap = att + ((size_t)h * 320 + iq0 + row) * 320 + k0 + c2;
                float v0 = ap[0], v1 = ap[1];
                ush2 h2, l2;
                h2[0] = f2b(v0); l2[0] = f2b(v0 - b2f(h2[0]));
                h2[1] = f2b(v1); l2[1] = f2b(v1 - b2f(h2[1]));
                *(ush2*)&a_hi[row][c2] = h2;
                *(ush2*)&a_lo[row][c2] = l2;
            }
            {
                int row = tid >> 2, seg = tid & 3;
                size_t off = ((size_t)h * 64 + row) * 320 + k0 + seg * 8;
                *(short8*)&B[row][seg * 8]      = *(const short8*)(vkv_hi + off);
                *(short8*)&B[64 + row][seg * 8] = *(const short8*)(vkv_lo + off);
            }
            __syncthreads();
            short8 afh = *(short8*)&a_hi[ncol][blk * 8];
            short8 afl = *(short8*)&a_lo[ncol][blk * 8];
            short8 bfh = *(short8*)&B[w * 16 + ncol][blk * 8];
            short8 bfl = *(short8*)&B[64 + w * 16 + ncol][blk * 8];
            acc = __builtin_amdgcn_mfma_f32_16x16x32_bf16(afh, bfh, acc, 0, 0, 0);
            acc = __builtin_amdgcn_mfma_f32_16x16x32_bf16(afh, bfl, acc, 0, 0, 0);
            acc = __builtin_amdgcn_mfma_f32_16x16x32_bf16(afl, bfh, acc, 0, 0, 0);
        }
        {
            int n = w * 16 + ncol;
            #pragma unroll
            for (int r = 0; r < 4; r++) {
                int iq = iq0 + mrow + r;
                float v = acc[r];
                if (n < 16) cc[(size_t)iq * 2400 + h * 16 + n] = v;
                else        ogsh[mrow + r][n - 16] = v;
            }
        }
        __syncthreads();
        if (tid < 128) {
            int iqr = tid >> 3, p = tid & 7;
            int l = iq0 + iqr;
            const float* R = rot + l * 9;
            float tx = trans[l * 3], ty = trans[l * 3 + 1], tz = trans[l * 3 + 2];
            const float* o = &ogsh[iqr][p * 6];
            float gx = o[0] - tx, gy = o[1] - ty, gz = o[2] - tz;
            float l0 = R[0] * gx + R[3] * gy + R[6] * gz;
            float l1 = R[1] * gx + R[4] * gy + R[7] * gz;
            float l2 = R[2] * gx + R[5] * gy + R[8] * gz;
            float dx = o[3], dy = o[4], dz = o[5];
            float e0 = R[0] * dx + R[3] * dy + R[6] * dz;
            float e1 = R[1] * dx + R[4] * dy + R[7] * dz;
            float e2 = R[2] * dx + R[5] * dy + R[8] * dz;
            float n = sqrtf(e0 * e0 + e1 * e1 + e2 * e2);
            float inv = 1.0f / fmaxf(n, 1e-12f);
            float ln = sqrtf(l0 * l0 + l1 * l1 + l2 * l2);
            float vals[7] = { l0, l1, l2, e0 * inv, e1 * inv, e2 * inv, ln };
            size_t base = (size_t)l * 2400 + 192 + (h * PV + p) * 7;
            #pragma unroll
            for (int j = 0; j < 7; j++) cc[base + j] = vals[j];
        }
    } else {
        int iq = bid - 240;
        int kp2 = (tid & 15) * 2;
        int cb = (tid >> 4) * 8;
        const float* zbase = z + ((size_t)iq * 320 + kp2) * 128 + cb;

        float4 zA0, zA1, zA2, zA3, zB0, zB1, zB2, zB3;
        {
            const float* p = zbase;
            zA0 = *(const float4*)(p);       zA1 = *(const float4*)(p + 4);
            zA2 = *(const float4*)(p + 128); zA3 = *(const float4*)(p + 132);
            p = zbase + (size_t)32 * 128;
            zB0 = *(const float4*)(p);       zB1 = *(const float4*)(p + 4);
            zB2 = *(const float4*)(p + 128); zB3 = *(const float4*)(p + 132);
        }

        f32x4 acc[2] = {};
        #pragma unroll
        for (int i = 0; i < 10; i++) {
            int k0 = i * 32;
            __syncthreads();
            {
                int row = tid >> 4, c2 = (tid & 15) * 2;
                float v0 = 0.f, v1 = 0.f;
                if (row < 12) {
                    const float* ap = att + ((size_t)row * 320 + iq) * 320 + k0 + c2;
                    v0 = ap[0]; v1 = ap[1];
                }
                ush2 h2, l2;
                h2[0] = f2b(v0); l2[0] = f2b(v0 - b2f(h2[0]));
                h2[1] = f2b(v1); l2[1] = f2b(v1 - b2f(h2[1]));
                *(ush2*)&a_hi[row][c2] = h2;
                *(ush2*)&a_lo[row][c2] = l2;
            }
            {
                float va[8], vb[8];
                if ((i & 1) == 0) {
                    va[0]=zA0.x; va[1]=zA0.y; va[2]=zA0.z; va[3]=zA0.w;
                    va[4]=zA1.x; va[5]=zA1.y; va[6]=zA1.z; va[7]=zA1.w;
                    vb[0]=zA2.x; vb[1]=zA2.y; vb[2]=zA2.z; vb[3]=zA2.w;
                    vb[4]=zA3.x; vb[5]=zA3.y; vb[6]=zA3.z; vb[7]=zA3.w;
                } else {
                    va[0]=zB0.x; va[1]=zB0.y; va[2]=zB0.z; va[3]=zB0.w;
                    va[4]=zB1.x; va[5]=zB1.y; va[6]=zB1.z; va[7]=zB1.w;
                    vb[0]=zB2.x; vb[1]=zB2.y; vb[2]=zB2.z; vb[3]=zB2.w;
                    vb[4]=zB3.x; vb[5]=zB3.y; vb[6]=zB3.z; vb[7]=zB3.w;
                }
                #pragma unroll
                for (int c = 0; c < 8; c++) {
                    ush2 pr;
                    pr[0] = f2b(va[c]);
                    pr[1] = f2b(vb[c]);
                    *(ush2*)&B[cb + c][kp2] = pr;
                }
                if (i + 2 < 10) {
                    const float* p = zbase + (size_t)(k0 + 64) * 128;
                    if ((i & 1) == 0) {
                        zA0 = *(const float4*)(p);       zA1 = *(const float4*)(p + 4);
                        zA2 = *(const float4*)(p + 128); zA3 = *(const float4*)(p + 132);
                    } else {
                        zB0 = *(const float4*)(p);       zB1 = *(const float4*)(p + 4);
                        zB2 = *(const float4*)(p + 128); zB3 = *(const float4*)(p + 132);
                    }
                }
            }
            __syncthreads();
            short8 afh = *(short8*)&a_hi[ncol][blk * 8];
            short8 afl = *(short8*)&a_lo[ncol][blk * 8];
            #pragma unroll
            for (int s2 = 0; s2 < 2; s2++) {
                short8 bf = *(short8*)&B[w * 32 + s2 * 16 + ncol][blk * 8];
                acc[s2] = __builtin_amdgcn_mfma_f32_16x16x32_bf16(afl, bf, acc[s2], 0, 0, 0);
                acc[s2] = __builtin_amdgcn_mfma_f32_16x16x32_bf16(afh, bf, acc[s2], 0, 0, 0);
            }
        }
        #pragma unroll
        for (int s2 = 0; s2 < 2; s2++) {
            int n = w * 32 + s2 * 16 + ncol;
            #pragma unroll
            for (int r = 0; r < 4; r++) {
                int h = mrow + r;
                if (h < 12)
                    cc[(size_t)iq * 2400 + 864 + (size_t)h * 128 + n] = acc[s2][r];
            }
        }
    }
}

// ---------------- kernel 5: partials = cc @ Wo; A split in-kernel ----------------
__global__ __launch_bounds__(256) void k_gemm(
    const float* __restrict__ cc,
    const unsigned short* __restrict__ woT_hi, const unsigned short* __restrict__ woT_lo,
    float* __restrict__ part)
{
    __shared__ unsigned short a_h[16][56], a_l[16][56];
    __shared__ unsigned short w_h[64][56], w_l[64][56];
    int iq0 = blockIdx.x * 16, col0 = blockIdx.y * 64, ks = blockIdx.z;
    int tid = threadIdx.x;
    int lane = tid & 63, w = tid >> 6;
    int ncol = lane & 15, blk = lane >> 4, mrow = (lane >> 4) * 4;

    f32x4 acc = {};
    for (int kc = 0; kc < 15; kc++) {
        int k0 = ks * 480 + kc * 32;
        __syncthreads();
        {
            int row = tid >> 4, c2 = (tid & 15) * 2;
            const float* ap = cc + (size_t)(iq0 + row) * 2400 + k0 + c2;
            float v0 = ap[0], v1 = ap[1];
            ush2 h2, l2;
            h2[0] = f2b(v0); l2[0] = f2b(v0 - b2f(h2[0]));
            h2[1] = f2b(v1); l2[1] = f2b(v1 - b2f(h2[1]));
            *(ush2*)&a_h[row][c2] = h2;
            *(ush2*)&a_l[row][c2] = l2;
        }
        #pragma unroll
        for (int t2 = 0; t2 < 2; t2++) {
            int idx = tid * 2 + t2;          // 0..511
            int arr = idx >> 8, i2 = idx & 255;
            int row = i2 >> 2, seg = i2 & 3;
            size_t off = (size_t)(col0 + row) * 2400 + k0 + seg * 8;
            if (arr == 0) *(short8*)&w_h[row][seg * 8] = *(const short8*)(woT_hi + off);
            else          *(short8*)&w_l[row][seg * 8] = *(const short8*)(woT_lo + off);
        }
        __syncthreads();
        short8 afh = *(short8*)&a_h[ncol][blk * 8];
        short8 afl = *(short8*)&a_l[ncol][blk * 8];
        short8 bfh = *(short8*)&w_h[w * 16 + ncol][blk * 8];
        short8 bfl = *(short8*)&w_l[w * 16 + ncol][blk * 8];
        acc = __builtin_amdgcn_mfma_f32_16x16x32_bf16(afh, bfh, acc, 0, 0, 0);
        acc = __builtin_amdgcn_mfma_f32_16x16x32_bf16(afh, bfl, acc, 0, 0, 0);
        acc = __builtin_amdgcn_mfma_f32_16x16x32_bf16(afl, bfh, acc, 0, 0, 0);
    }
    {
        int cn = col0 + w * 16 + ncol;
        #pragma unroll
        for (int r = 0; r < 4; r++)
            part[((size_t)ks * 320 + iq0 + mrow + r) * 384 + cn] = acc[r];
    }
}

// ---------------- kernel 6: out = bo + sum of 5 partials (deterministic) ----------
__global__ __launch_bounds__(256) void k_reduce(
    const float* __restrict__ part, const float* __restrict__ bo, float* __restrict__ out)
{
    int i = blockIdx.x * 256 + threadIdx.x;   // < 122880
    float v = bo[i % CS];
    #pragma unroll
    for (int ks = 0; ks < 5; ks++) v += part[(size_t)ks * 122880 + i];
    out[i] = v;
}

extern "C" void kernel_launch(void* const* d_in, const int* in_sizes, int n_in,
                              void* d_out, int out_size, void* d_ws, size_t ws_size,
                              hipStream_t stream)
{
    const float* s     = (const float*)d_in[0];
    const float* rot   = (const float*)d_in[1];
    const float* trans = (const float*)d_in[2];
    const float* z     = (const float*)d_in[3];
    const float* fm    = (const float*)d_in[4];
    const float* Wq    = (const float*)d_in[5];
    const float* bq    = (const float*)d_in[6];
    const float* Wkv   = (const float*)d_in[7];
    const float* bkv   = (const float*)d_in[8];
    const float* Wqp   = (const float*)d_in[9];
    const float* bqp   = (const float*)d_in[10];
    const float* Wkvp  = (const float*)d_in[11];
    const float* bkvp  = (const float*)d_in[12];
    const float* Wg    = (const float*)d_in[13];
    const float* bg    = (const float*)d_in[14];
    const float* gw    = (const float*)d_in[15];
    const float* dw    = (const float*)d_in[16];
    const float* hw    = (const float*)d_in[17];
    const float* Wo    = (const float*)d_in[18];
    const float* bo    = (const float*)d_in[19];

    float* ws = (float*)d_ws;
    float*          q       = ws + OFF_Q;
    float*          kv      = ws + OFF_KV;
    float*          qpt     = ws + OFF_QPT;
    float*          att     = ws + OFF_ATTHI;
    float*          part    = ws + OFF_PARTG;
    float*          cc      = ws + OFF_CCHI;
    unsigned short* s_hi    = (unsigned short*)(ws + OFF_SHI);
    unsigned short* s_mid   = (unsigned short*)(ws + OFF_SMID);
    unsigned short* s_lo    = (unsigned short*)(ws + OFF_SLO);
    float*          bcat    = ws + OFF_BCAT;
    unsigned short* vkv_hi  = (unsigned short*)(ws + OFF_VKVHI);
    unsigned short* vkv_lo  = (unsigned short*)(ws + OFF_VKVLO);
    float*          qpr     = ws + OFF_QPR;
    float*          kvpr    = ws + OFF_KVPR;
    float*          gate    = ws + OFF_GATE;
    float*          krow    = ws + OFF_KROW;
    unsigned short* wcT_hi  = (unsigned short*)(ws + OFF_WCTHI);
    unsigned short* wcT_mid = (unsigned short*)(ws + OFF_WCTMID);
    unsigned short* wcT_lo  = (unsigned short*)(ws + OFF_WCTLO);
    unsigned short* woT_hi  = (unsigned short*)(ws + OFF_WOTHI);
    unsigned short* woT_lo  = (unsigned short*)(ws + OFF_WOTLO);
    float* out = (float*)d_out;

    k_prep<<<dim3(883), dim3(256), 0, stream>>>(s, Wq, bq, Wkv, bkv, Wqp, bqp,
                                                Wkvp, bkvp, Wg, bg, Wo,
                                                s_hi, s_mid, s_lo, bcat,
                                                wcT_hi, wcT_mid, wcT_lo, woT_hi, woT_lo);
    k_proj<<<dim3(37, 20), dim3(192), 0, stream>>>(s_hi, s_mid, s_lo, wcT_hi, wcT_mid, wcT_lo,
                                                   bcat, q, kv, qpr, kvpr, gate);
    k_points<<<dim3(LSEQ), dim3(256), 0, stream>>>(qpr, kvpr, gate, rot, trans, kv,
                                                   qpt, krow, vkv_hi, vkv_lo);
    k_att<<<dim3(40, NH), dim3(256), 0, stream>>>(q, qpt, krow, fm, gw, dw, hw, att);
    k_svpair<<<dim3(560), dim3(256), 0, stream>>>(att, vkv_hi, vkv_lo, z, rot, trans, cc);
    k_gemm<<<dim3(20, 6, 5), dim3(256), 0, stream>>>(cc, woT_hi, woT_lo, part);
    k_reduce<<<dim3(480), dim3(256), 0, stream>>>(part, bo, out);
}

// Round 10
// 205.552 us; speedup vs baseline: 1.0995x; 1.0136x over previous
//
#include <hip/hip_runtime.h>
#include <hip/hip_bf16.h>
#include <math.h>

#define LSEQ 320
#define CS 384
#define CZ 128
#define CH 16
#define NH 12
#define PQ 4
#define PV 8
#define EPSF 1e-8f

typedef short short8 __attribute__((ext_vector_type(8)));
typedef float f32x4 __attribute__((ext_vector_type(4)));
typedef unsigned short ush2 __attribute__((ext_vector_type(2)));

// float -> bf16 (RNE)
__device__ __forceinline__ unsigned short f2b(float x) {
    union { float f; unsigned u; } v; v.f = x;
    unsigned r = (v.u + 0x7FFF + ((v.u >> 16) & 1)) >> 16;
    return (unsigned short)r;
}
__device__ __forceinline__ float b2f(unsigned short h) {
    union { unsigned u; float f; } v; v.u = ((unsigned)h) << 16;
    return v.f;
}

// workspace float offsets
#define OFF_Q       0
#define OFF_KV      61440
#define OFF_QPT     184320
#define OFF_SHI     276480
#define OFF_SMID    337920
#define OFF_SLO     399360
#define OFF_ATTHI   552960
#define OFF_PARTG   552960
#define OFF_CCHI    2191360
#define OFF_BCAT    4074496
#define OFF_VKVHI   4997872
#define OFF_VKVLO   5120752
#define OFF_QPR     5243632
#define OFF_KVPR    5335792
#define OFF_GATE    5612272
#define OFF_KROW    6242032
#define OFF_WCTHI   6426352
#define OFF_WCTMID  6767344
#define OFF_WCTLO   7108336
#define OFF_WOTHI   7449328
#define OFF_WOTLO   7910128

// ---------------- kernel 0: fused weight split/transpose + cast s + bcat ---------
// bid < 168: wc transpose (heavy, first).  168..395: wo transpose.  else: s cast.
__global__ __launch_bounds__(256) void k_prep(
    const float* __restrict__ s,
    const float* __restrict__ Wq, const float* __restrict__ bq,
    const float* __restrict__ Wkv, const float* __restrict__ bkv,
    const float* __restrict__ Wqp, const float* __restrict__ bqp,
    const float* __restrict__ Wkvp, const float* __restrict__ bkvp,
    const float* __restrict__ Wg, const float* __restrict__ bg,
    const float* __restrict__ Wo,
    unsigned short* __restrict__ s_hi, unsigned short* __restrict__ s_mid,
    unsigned short* __restrict__ s_lo, float* __restrict__ bcat,
    unsigned short* __restrict__ wcT_hi, unsigned short* __restrict__ wcT_mid,
    unsigned short* __restrict__ wcT_lo,
    unsigned short* __restrict__ woT_hi, unsigned short* __restrict__ woT_lo)
{
    __shared__ unsigned short th[64][65], tm[64][65], tl[64][65];
    int bid = blockIdx.x, tid = threadIdx.x;
    if (bid < 168) {
        int k0 = (bid % 6) * 64, c0 = (bid / 6) * 64;
        #pragma unroll
        for (int rep = 0; rep < 16; rep++) {
            int idx = rep * 256 + tid;
            int i = idx >> 6, j = idx & 63;    // i = k-off, j = c-off
            int c = c0 + j, k = k0 + i;
            float v = 0.f;
            if (c < 1776) {
                if (c < 192)       v = Wq[(size_t)k * 192 + c];
                else if (c < 576)  v = Wkv[(size_t)k * 384 + c - 192];
                else if (c < 864)  v = Wqp[(size_t)k * 288 + c - 576];
                else if (c < 1728) v = Wkvp[(size_t)k * 864 + c - 864];
                else               v = Wg[(size_t)k * 48 + c - 1728];
            }
            unsigned short hi = f2b(v);
            float r1 = v - b2f(hi);
            unsigned short mid = f2b(r1);
            th[i][j] = hi; tm[i][j] = mid; tl[i][j] = f2b(r1 - b2f(mid));
        }
        __syncthreads();
        #pragma unroll
        for (int rep = 0; rep < 16; rep++) {
            int idx = rep * 256 + tid;
            int i = idx >> 6, j = idx & 63;    // i = c-off, j = k-off
            int c = c0 + i;
            if (c < 1776) {
                size_t o = (size_t)c * 384 + k0 + j;
                wcT_hi[o] = th[j][i]; wcT_mid[o] = tm[j][i]; wcT_lo[o] = tl[j][i];
            }
        }
        return;
    }
    if (bid < 396) {
        int b = bid - 168;
        int r0 = (b % 38) * 64, c0 = (b / 38) * 64;
        #pragma unroll
        for (int rep = 0; rep < 16; rep++) {
            int idx = rep * 256 + tid;
            int i = idx >> 6, j = idx & 63;    // i = r-off, j = c-off
            int r = r0 + i;
            float v = 0.f;
            if (r < 2400) v = Wo[(size_t)r * 384 + c0 + j];
            unsigned short hi = f2b(v);
            th[i][j] = hi; tl[i][j] = f2b(v - b2f(hi));
        }
        __syncthreads();
        #pragma unroll
        for (int rep = 0; rep < 16; rep++) {
            int idx = rep * 256 + tid;
            int i = idx >> 6, j = idx & 63;    // i = c-off, j = r-off
            int r = r0 + j;
            if (r < 2400) {
                size_t o = (size_t)(c0 + i) * 2400 + r;
                woT_hi[o] = th[j][i]; woT_lo[o] = tl[j][i];
            }
        }
        return;
    }
    int i = (bid - 396) * 256 + tid;
    if (i < 122880) {
        float x = s[i];
        unsigned short hi = f2b(x);
        float r1 = x - b2f(hi);
        unsigned short mid = f2b(r1);
        s_hi[i] = hi; s_mid[i] = mid; s_lo[i] = f2b(r1 - b2f(mid));
        return;
    }
    i -= 122880;
    if (i < 1776) {
        float v;
        if (i < 192)       v = bq[i];
        else if (i < 576)  v = bkv[i - 192];
        else if (i < 864)  v = bqp[i - 576];
        else if (i < 1728) v = bkvp[i - 864];
        else               v = bg[i - 1728];
        bcat[i] = v;
    }
}

// ---------------- kernel 1: projection GEMM, 3-way split MFMA, m=16 tiles ---------
__global__ __launch_bounds__(192) void k_proj(
    const unsigned short* __restrict__ s_hi, const unsigned short* __restrict__ s_mid,
    const unsigned short* __restrict__ s_lo,
    const unsigned short* __restrict__ wcT_hi, const unsigned short* __restrict__ wcT_mid,
    const unsigned short* __restrict__ wcT_lo,
    const float* __restrict__ bcat,
    float* __restrict__ qo, float* __restrict__ kvo,
    float* __restrict__ qpr, float* __restrict__ kvpr, float* __restrict__ gate)
{
    __shared__ unsigned short a_h[16][56], a_m[16][56], a_l[16][56];
    __shared__ unsigned short w_h[48][56], w_m[48][56], w_l[48][56];
    int col0 = blockIdx.x * 48, l0 = blockIdx.y * 16;
    int tid = threadIdx.x;
    int lane = tid & 63, w = tid >> 6;
    int ncol = lane & 15, blk = lane >> 4, mrow = (lane >> 4) * 4;

    float* dst; int nc, cbase; bool sig = false;
    if (col0 < 192)       { nc = 192; cbase = col0;        dst = qo;   }
    else if (col0 < 576)  { nc = 384; cbase = col0 - 192;  dst = kvo;  }
    else if (col0 < 864)  { nc = 288; cbase = col0 - 576;  dst = qpr;  }
    else if (col0 < 1728) { nc = 864; cbase = col0 - 864;  dst = kvpr; }
    else                  { nc = 48;  cbase = 0;           dst = gate; sig = true; }

    f32x4 acc = {};
    for (int k0 = 0; k0 < 384; k0 += 32) {
        __syncthreads();
        {
            int arr = tid >> 6, idx = tid & 63;
            int row = idx >> 2, seg = idx & 3;
            size_t off = (size_t)(l0 + row) * 384 + k0 + seg * 8;
            if (arr == 0)      *(short8*)&a_h[row][seg * 8] = *(const short8*)(s_hi + off);
            else if (arr == 1) *(short8*)&a_m[row][seg * 8] = *(const short8*)(s_mid + off);
            else               *(short8*)&a_l[row][seg * 8] = *(const short8*)(s_lo + off);
        }
        {
            int row = tid >> 2, seg = tid & 3;
            size_t off = (size_t)(col0 + row) * 384 + k0 + seg * 8;
            *(short8*)&w_h[row][seg * 8] = *(const short8*)(wcT_hi + off);
            *(short8*)&w_m[row][seg * 8] = *(const short8*)(wcT_mid + off);
            *(short8*)&w_l[row][seg * 8] = *(const short8*)(wcT_lo + off);
        }
        __syncthreads();
        short8 afh = *(short8*)&a_h[ncol][blk * 8];
        short8 afm = *(short8*)&a_m[ncol][blk * 8];
        short8 afl = *(short8*)&a_l[ncol][blk * 8];
        short8 bfh = *(short8*)&w_h[w * 16 + ncol][blk * 8];
        short8 bfm = *(short8*)&w_m[w * 16 + ncol][blk * 8];
        short8 bfl = *(short8*)&w_l[w * 16 + ncol][blk * 8];
        acc = __builtin_amdgcn_mfma_f32_16x16x32_bf16(afm, bfm, acc, 0, 0, 0);
        acc = __builtin_amdgcn_mfma_f32_16x16x32_bf16(afh, bfl, acc, 0, 0, 0);
        acc = __builtin_amdgcn_mfma_f32_16x16x32_bf16(afl, bfh, acc, 0, 0, 0);
        acc = __builtin_amdgcn_mfma_f32_16x16x32_bf16(afh, bfm, acc, 0, 0, 0);
        acc = __builtin_amdgcn_mfma_f32_16x16x32_bf16(afm, bfh, acc, 0, 0, 0);
        acc = __builtin_amdgcn_mfma_f32_16x16x32_bf16(afh, bfh, acc, 0, 0, 0);
    }
    {
        int n = w * 16 + ncol;
        float bv = bcat[col0 + n];
        int cloc = cbase + n;
        #pragma unroll
        for (int r = 0; r < 4; r++) {
            float v2 = acc[r] + bv;
            if (sig) v2 = 1.0f / (1.0f + expf(-v2));
            dst[(size_t)(l0 + mrow + r) * nc + cloc] = v2;
        }
    }
}

// ---------------- kernel 2: frame transforms + vkvT hi/lo + krowT table ----------
// krowT layout: [h][j][kk]  (j-major so k_att lane reads are coalesced)
__global__ __launch_bounds__(256) void k_points(
    const float* __restrict__ qpr, const float* __restrict__ kvpr, const float* __restrict__ gate,
    const float* __restrict__ rot, const float* __restrict__ trans,
    const float* __restrict__ kv,
    float* __restrict__ qpt, float* __restrict__ krowT,
    unsigned short* __restrict__ vkv_hi, unsigned short* __restrict__ vkv_lo)
{
    __shared__ float vsh[96][6];
    __shared__ float kp_s[48][6];
    __shared__ float kn_s[48];
    int l = blockIdx.x, t = threadIdx.x;
    const float* R = rot + l * 9;
    float tx = trans[l * 3], ty = trans[l * 3 + 1], tz = trans[l * 3 + 2];
    if (t < 192) {
        const float* src; float g = 1.0f; float* dst = nullptr; int vj = -1, kj = -1;
        if (t < 48)      { src = qpr + (size_t)l * 288 + t * 6; g = gate[l * 48 + t]; dst = qpt + ((size_t)l * 48 + t) * 6; }
        else if (t < 96) { kj = t - 48; src = kvpr + (size_t)l * 864 + kj * 6; }
        else             { int j = t - 96; src = kvpr + (size_t)l * 864 + 288 + j * 6; vj = j; }
        float px = src[0], py = src[1], pz = src[2], ux = src[3], uy = src[4], uz = src[5];
        float c0 = R[0] * px + R[1] * py + R[2] * pz + tx;
        float c1 = R[3] * px + R[4] * py + R[5] * pz + ty;
        float c2 = R[6] * px + R[7] * py + R[8] * pz + tz;
        float d0 = R[0] * ux + R[1] * uy + R[2] * uz;
        float d1 = R[3] * ux + R[4] * uy + R[5] * uz;
        float d2 = R[6] * ux + R[7] * uy + R[8] * uz;
        if (vj >= 0) {
            vsh[vj][0] = c0; vsh[vj][1] = c1; vsh[vj][2] = c2;
            vsh[vj][3] = d0; vsh[vj][4] = d1; vsh[vj][5] = d2;
        } else if (kj >= 0) {
            kp_s[kj][0] = c0; kp_s[kj][1] = c1; kp_s[kj][2] = c2;
            kp_s[kj][3] = d0; kp_s[kj][4] = d1; kp_s[kj][5] = d2;
            kn_s[kj] = sqrtf(d0 * d0 + d1 * d1 + d2 * d2);
        } else {
            dst[0] = c0 * g; dst[1] = c1 * g; dst[2] = c2 * g;
            dst[3] = d0 * g; dst[4] = d1 * g; dst[5] = d2 * g;
        }
    }
    __syncthreads();
    #pragma unroll
    for (int e = 0; e < 3; e++) {
        int u = t * 3 + e;   // < 768
        int h = u >> 6, n = u & 63;
        float val;
        if (n < 16) val = kv[(size_t)l * 384 + 192 + h * 16 + n];
        else        val = vsh[h * 8 + (n - 16) / 6][(n - 16) % 6];
        unsigned short hi = f2b(val);
        size_t idx = ((size_t)h * 64 + n) * 320 + l;
        vkv_hi[idx] = hi;
        vkv_lo[idx] = f2b(val - b2f(hi));
    }
    for (int idx = t; idx < 576; idx += 256) {
        int h = idx / 48, j = idx - h * 48;
        float v;
        if (j < 24)      v = kp_s[h * 4 + j / 6][j % 6];
        else if (j < 40) v = kv[(size_t)l * 384 + h * 16 + (j - 24)];
        else if (j < 44) v = kn_s[h * 4 + (j - 40)];
        else             v = 0.0f;
        krowT[((size_t)h * 48 + j) * 320 + l] = v;
    }
}

// ---------------- kernel 3: attention logits + softmax; coalesced krowT reads ----
__global__ __launch_bounds__(256) void k_att(
    const float* __restrict__ qb, const float* __restrict__ qpt,
    const float* __restrict__ krowT,
    const float* __restrict__ fm, const float* __restrict__ gw,
    const float* __restrict__ dwp, const float* __restrict__ hwp,
    float* __restrict__ att)
{
    int tid = threadIdx.x;
    int w = tid >> 6, lane = tid & 63;
    int iqA = blockIdx.x * 8 + w * 2;
    int iqB = iqA + 1;
    int h = blockIdx.y;

    float qvA[CH], qvB[CH];
    #pragma unroll
    for (int c = 0; c < CH; c++) {
        qvA[c] = qb[(size_t)iqA * 192 + h * CH + c];
        qvB[c] = qb[(size_t)iqB * 192 + h * CH + c];
    }
    float qpA[24], qpB[24];
    #pragma unroll
    for (int j = 0; j < 24; j++) {
        qpA[j] = qpt[(size_t)iqA * 288 + h * 24 + j];
        qpB[j] = qpt[(size_t)iqB * 288 + h * 24 + j];
    }
    float nqA[PQ], nq2A[PQ], nqB[PQ], nq2B[PQ];
    #pragma unroll
    for (int p = 0; p < PQ; p++) {
        float x = qpA[p * 6 + 3], y = qpA[p * 6 + 4], zz = qpA[p * 6 + 5];
        nq2A[p] = x * x + y * y + zz * zz; nqA[p] = sqrtf(nq2A[p]);
        x = qpB[p * 6 + 3]; y = qpB[p * 6 + 4]; zz = qpB[p * 6 + 5];
        nq2B[p] = x * x + y * y + zz * zz; nqB[p] = sqrtf(nq2B[p]);
    }
    float dwv = dwp[0], g0 = gw[0], g1 = gw[1], hwv = hwp[h];
    float fmA = fm[iqA], fmB = fm[iqB];

    float lgA[5], lgB[5];
    for (int r = 0; r < 5; r++) {
        int kk = r * 64 + lane;
        const float* colp = krowT + (size_t)h * 48 * 320 + kk;
        float rw[44];
        #pragma unroll
        for (int j = 0; j < 44; j++) rw[j] = colp[(size_t)j * 320];
        float fmk = fm[kk];

        #pragma unroll
        for (int which = 0; which < 2; which++) {
            const float* qp = which ? qpB : qpA;
            const float* qv = which ? qvB : qvA;
            const float* nq = which ? nqB : nqA;
            const float* nq2 = which ? nq2B : nq2A;
            float fmi = which ? fmB : fmA;

            float scalar = 0.f;
            #pragma unroll
            for (int c = 0; c < CH; c++) scalar += qv[c] * rw[24 + c];
            scalar *= 0.25f;

            float pos = 0.f;
            #pragma unroll
            for (int p = 0; p < PQ; p++) {
                float dx = qp[p * 6] - rw[p * 6];
                float dy = qp[p * 6 + 1] - rw[p * 6 + 1];
                float dz = qp[p * 6 + 2] - rw[p * 6 + 2];
                float d = __builtin_amdgcn_sqrtf(dx * dx + dy * dy + dz * dz);
                float de = d + EPSF;
                pos += d + __logf(de) + __builtin_amdgcn_rcpf(de);
            }
            pos *= 0.25f;

            float dir = 0.f;
            #pragma unroll
            for (int p = 0; p < PQ; p++) {
                float kx = rw[p * 6 + 3], ky = rw[p * 6 + 4], kz = rw[p * 6 + 5];
                float nk = rw[40 + p];
                float nk2 = nk * nk;
                float cm = 0.f, dself = 0.f;
                #pragma unroll
                for (int pq = 0; pq < PQ; pq++) {
                    float dq = qp[pq * 6 + 3] * kx + qp[pq * 6 + 4] * ky + qp[pq * 6 + 5] * kz;
                    if (pq == p) dself = dq;
                    cm += __builtin_amdgcn_sqrtf(fmaxf(nq2[pq] * nk2 - dq * dq, 0.0f));
                }
                cm *= 0.25f;
                dir += dself - cm * __builtin_amdgcn_rcpf(nq[p] * nk + EPSF);
            }
            dir *= 0.25f;

            float logit = scalar + dwv * (g0 * pos + g1 * dir);
            logit *= hwv;
            logit += 100000.0f * (fmi * fmk - 1.0f);
            if (which) lgB[r] = logit; else lgA[r] = logit;
        }
    }

    // softmax A
    float mxA = lgA[0];
    #pragma unroll
    for (int r = 1; r < 5; r++) mxA = fmaxf(mxA, lgA[r]);
    for (int m = 32; m; m >>= 1) mxA = fmaxf(mxA, __shfl_xor(mxA, m, 64));
    float eA[5], smA = 0.f;
    #pragma unroll
    for (int r = 0; r < 5; r++) { eA[r] = __expf(lgA[r] - mxA); smA += eA[r]; }
    for (int m = 32; m; m >>= 1) smA += __shfl_xor(smA, m, 64);
    float invA = 1.0f / smA;
    #pragma unroll
    for (int r = 0; r < 5; r++)
        att[((size_t)h * 320 + iqA) * 320 + r * 64 + lane] = eA[r] * invA;
    // softmax B
    float mxB = lgB[0];
    #pragma unroll
    for (int r = 1; r < 5; r++) mxB = fmaxf(mxB, lgB[r]);
    for (int m = 32; m; m >>= 1) mxB = fmaxf(mxB, __shfl_xor(mxB, m, 64));
    float eB[5], smB = 0.f;
    #pragma unroll
    for (int r = 0; r < 5; r++) { eB[r] = __expf(lgB[r] - mxB); smB += eB[r]; }
    for (int m = 32; m; m >>= 1) smB += __shfl_xor(smB, m, 64);
    float invB = 1.0f / smB;
    #pragma unroll
    for (int r = 0; r < 5; r++)
        att[((size_t)h * 320 + iqB) * 320 + r * 64 + lane] = eB[r] * invB;
}

// ---------------- kernel 4: fused pair (bid<320, heavy first) + sv (bid>=320) ----
__global__ __launch_bounds__(256) void k_svpair(
    const float* __restrict__ att,   // [12][320][320]
    const unsigned short* __restrict__ vkv_hi, const unsigned short* __restrict__ vkv_lo,
    const float* __restrict__ z,     // [320][320][128]
    const float* __restrict__ rot, const float* __restrict__ trans,
    float* __restrict__ cc)          // [320][2400]
{
    __shared__ unsigned short a_hi[16][56];
    __shared__ unsigned short a_lo[16][56];
    __shared__ unsigned short B[128][56];
    __shared__ float ogsh[16][49];
    int bid = blockIdx.x;
    int tid = threadIdx.x;
    int lane = tid & 63, w = tid >> 6;
    int ncol = lane & 15, blk = lane >> 4, mrow = (lane >> 4) * 4;

    if (bid < 320) {
        int iq = bid;
        int kp2 = (tid & 15) * 2;
        int cb = (tid >> 4) * 8;
        const float* zbase = z + ((size_t)iq * 320 + kp2) * 128 + cb;

        float4 zA0, zA1, zA2, zA3, zB0, zB1, zB2, zB3;
        {
            const float* p = zbase;
            zA0 = *(const float4*)(p);       zA1 = *(const float4*)(p + 4);
            zA2 = *(const float4*)(p + 128); zA3 = *(const float4*)(p + 132);
            p = zbase + (size_t)32 * 128;
            zB0 = *(const float4*)(p);       zB1 = *(const float4*)(p + 4);
            zB2 = *(const float4*)(p + 128); zB3 = *(const float4*)(p + 132);
        }

        f32x4 acc[2] = {};
        #pragma unroll
        for (int i = 0; i < 10; i++) {
            int k0 = i * 32;
            __syncthreads();
            {
                int row = tid >> 4, c2 = (tid & 15) * 2;
                float v0 = 0.f, v1 = 0.f;
                if (row < 12) {
                    const float* ap = att + ((size_t)row * 320 + iq) * 320 + k0 + c2;
                    v0 = ap[0]; v1 = ap[1];
                }
                ush2 h2, l2;
                h2[0] = f2b(v0); l2[0] = f2b(v0 - b2f(h2[0]));
                h2[1] = f2b(v1); l2[1] = f2b(v1 - b2f(h2[1]));
                *(ush2*)&a_hi[row][c2] = h2;
                *(ush2*)&a_lo[row][c2] = l2;
            }
            {
                float va[8], vb[8];
                if ((i & 1) == 0) {
                    va[0]=zA0.x; va[1]=zA0.y; va[2]=zA0.z; va[3]=zA0.w;
                    va[4]=zA1.x; va[5]=zA1.y; va[6]=zA1.z; va[7]=zA1.w;
                    vb[0]=zA2.x; vb[1]=zA2.y; vb[2]=zA2.z; vb[3]=zA2.w;
                    vb[4]=zA3.x; vb[5]=zA3.y; vb[6]=zA3.z; vb[7]=zA3.w;
                } else {
                    va[0]=zB0.x; va[1]=zB0.y; va[2]=zB0.z; va[3]=zB0.w;
                    va[4]=zB1.x; va[5]=zB1.y; va[6]=zB1.z; va[7]=zB1.w;
                    vb[0]=zB2.x; vb[1]=zB2.y; vb[2]=zB2.z; vb[3]=zB2.w;
                    vb[4]=zB3.x; vb[5]=zB3.y; vb[6]=zB3.z; vb[7]=zB3.w;
                }
                #pragma unroll
                for (int c = 0; c < 8; c++) {
                    ush2 pr;
                    pr[0] = f2b(va[c]);
                    pr[1] = f2b(vb[c]);
                    *(ush2*)&B[cb + c][kp2] = pr;
                }
                if (i + 2 < 10) {
                    const float* p = zbase + (size_t)(k0 + 64) * 128;
                    if ((i & 1) == 0) {
                        zA0 = *(const float4*)(p);       zA1 = *(const float4*)(p + 4);
                        zA2 = *(const float4*)(p + 128); zA3 = *(const float4*)(p + 132);
                    } else {
                        zB0 = *(const float4*)(p);       zB1 = *(const float4*)(p + 4);
                        zB2 = *(const float4*)(p + 128); zB3 = *(const float4*)(p + 132);
                    }
                }
            }
            __syncthreads();
            short8 afh = *(short8*)&a_hi[ncol][blk * 8];
            short8 afl = *(short8*)&a_lo[ncol][blk * 8];
            #pragma unroll
            for (int s2 = 0; s2 < 2; s2++) {
                short8 bf = *(short8*)&B[w * 32 + s2 * 16 + ncol][blk * 8];
                acc[s2] = __builtin_amdgcn_mfma_f32_16x16x32_bf16(afl, bf, acc[s2], 0, 0, 0);
                acc[s2] = __builtin_amdgcn_mfma_f32_16x16x32_bf16(afh, bf, acc[s2], 0, 0, 0);
            }
        }
        #pragma unroll
        for (int s2 = 0; s2 < 2; s2++) {
            int n = w * 32 + s2 * 16 + ncol;
            #pragma unroll
            for (int r = 0; r < 4; r++) {
                int h = mrow + r;
                if (h < 12)
                    cc[(size_t)iq * 2400 + 864 + (size_t)h * 128 + n] = acc[s2][r];
            }
        }
    } else {
        int b = bid - 320;
        int iq0 = (b % 20) * 16, h = b / 20;
        f32x4 acc = {};
        for (int k0 = 0; k0 < 320; k0 += 32) {
            __syncthreads();
            {
                int row = tid >> 4, c2 = (tid & 15) * 2;
                const float* ap = att + ((size_t)h * 320 + iq0 + row) * 320 + k0 + c2;
                float v0 = ap[0], v1 = ap[1];
                ush2 h2, l2;
                h2[0] = f2b(v0); l2[0] = f2b(v0 - b2f(h2[0]));
                h2[1] = f2b(v1); l2[1] = f2b(v1 - b2f(h2[1]));
                *(ush2*)&a_hi[row][c2] = h2;
                *(ush2*)&a_lo[row][c2] = l2;
            }
            {
                int row = tid >> 2, seg = tid & 3;
                size_t off = ((size_t)h * 64 + row) * 320 + k0 + seg * 8;
                *(short8*)&B[row][seg * 8]      = *(const short8*)(vkv_hi + off);
                *(short8*)&B[64 + row][seg * 8] = *(const short8*)(vkv_lo + off);
            }
            __syncthreads();
            short8 afh = *(short8*)&a_hi[ncol][blk * 8];
            short8 afl = *(short8*)&a_lo[ncol][blk * 8];
            short8 bfh = *(short8*)&B[w * 16 + ncol][blk * 8];
            short8 bfl = *(short8*)&B[64 + w * 16 + ncol][blk * 8];
            acc = __builtin_amdgcn_mfma_f32_16x16x32_bf16(afh, bfh, acc, 0, 0, 0);
            acc = __builtin_amdgcn_mfma_f32_16x16x32_bf16(afh, bfl, acc, 0, 0, 0);
            acc = __builtin_amdgcn_mfma_f32_16x16x32_bf16(afl, bfh, acc, 0, 0, 0);
        }
        {
            int n = w * 16 + ncol;
            #pragma unroll
            for (int r = 0; r < 4; r++) {
                int iq = iq0 + mrow + r;
                float v = acc[r];
                if (n < 16) cc[(size_t)iq * 2400 + h * 16 + n] = v;
                else        ogsh[mrow + r][n - 16] = v;
            }
        }
        __syncthreads();
        if (tid < 128) {
            int iqr = tid >> 3, p = tid & 7;
            int l = iq0 + iqr;
            const float* R = rot + l * 9;
            float tx = trans[l * 3], ty = trans[l * 3 + 1], tz = trans[l * 3 + 2];
            const float* o = &ogsh[iqr][p * 6];
            float gx = o[0] - tx, gy = o[1] - ty, gz = o[2] - tz;
            float l0 = R[0] * gx + R[3] * gy + R[6] * gz;
            float l1 = R[1] * gx + R[4] * gy + R[7] * gz;
            float l2 = R[2] * gx + R[5] * gy + R[8] * gz;
            float dx = o[3], dy = o[4], dz = o[5];
            float e0 = R[0] * dx + R[3] * dy + R[6] * dz;
            float e1 = R[1] * dx + R[4] * dy + R[7] * dz;
            float e2 = R[2] * dx + R[5] * dy + R[8] * dz;
            float n = sqrtf(e0 * e0 + e1 * e1 + e2 * e2);
            float inv = 1.0f / fmaxf(n, 1e-12f);
            float ln = sqrtf(l0 * l0 + l1 * l1 + l2 * l2);
            float vals[7] = { l0, l1, l2, e0 * inv, e1 * inv, e2 * inv, ln };
            size_t base = (size_t)l * 2400 + 192 + (h * PV + p) * 7;
            #pragma unroll
            for (int j = 0; j < 7; j++) cc[base + j] = vals[j];
        }
    }
}

// ---------------- kernel 5: partials = cc @ Wo; A split in-kernel ----------------
__global__ __launch_bounds__(256) void k_gemm(
    const float* __restrict__ cc,
    const unsigned short* __restrict__ woT_hi, const unsigned short* __restrict__ woT_lo,
    float* __restrict__ part)
{
    __shared__ unsigned short a_h[16][56], a_l[16][56];
    __shared__ unsigned short w_h[64][56], w_l[64][56];
    int iq0 = blockIdx.x * 16, col0 = blockIdx.y * 64, ks = blockIdx.z;
    int tid = threadIdx.x;
    int lane = tid & 63, w = tid >> 6;
    int ncol = lane & 15, blk = lane >> 4, mrow = (lane >> 4) * 4;

    f32x4 acc = {};
    for (int kc = 0; kc < 15; kc++) {
        int k0 = ks * 480 + kc * 32;
        __syncthreads();
        {
            int row = tid >> 4, c2 = (tid & 15) * 2;
            const float* ap = cc + (size_t)(iq0 + row) * 2400 + k0 + c2;
            float v0 = ap[0], v1 = ap[1];
            ush2 h2, l2;
            h2[0] = f2b(v0); l2[0] = f2b(v0 - b2f(h2[0]));
            h2[1] = f2b(v1); l2[1] = f2b(v1 - b2f(h2[1]));
            *(ush2*)&a_h[row][c2] = h2;
            *(ush2*)&a_l[row][c2] = l2;
        }
        #pragma unroll
        for (int t2 = 0; t2 < 2; t2++) {
            int idx = tid * 2 + t2;          // 0..511
            int arr = idx >> 8, i2 = idx & 255;
            int row = i2 >> 2, seg = i2 & 3;
            size_t off = (size_t)(col0 + row) * 2400 + k0 + seg * 8;
            if (arr == 0) *(short8*)&w_h[row][seg * 8] = *(const short8*)(woT_hi + off);
            else          *(short8*)&w_l[row][seg * 8] = *(const short8*)(woT_lo + off);
        }
        __syncthreads();
        short8 afh = *(short8*)&a_h[ncol][blk * 8];
        short8 afl = *(short8*)&a_l[ncol][blk * 8];
        short8 bfh = *(short8*)&w_h[w * 16 + ncol][blk * 8];
        short8 bfl = *(short8*)&w_l[w * 16 + ncol][blk * 8];
        acc = __builtin_amdgcn_mfma_f32_16x16x32_bf16(afh, bfh, acc, 0, 0, 0);
        acc = __builtin_amdgcn_mfma_f32_16x16x32_bf16(afh, bfl, acc, 0, 0, 0);
        acc = __builtin_amdgcn_mfma_f32_16x16x32_bf16(afl, bfh, acc, 0, 0, 0);
    }
    {
        int cn = col0 + w * 16 + ncol;
        #pragma unroll
        for (int r = 0; r < 4; r++)
            part[((size_t)ks * 320 + iq0 + mrow + r) * 384 + cn] = acc[r];
    }
}

// ---------------- kernel 6: out = bo + sum of 5 partials (deterministic) ----------
__global__ __launch_bounds__(256) void k_reduce(
    const float* __restrict__ part, const float* __restrict__ bo, float* __restrict__ out)
{
    int i = blockIdx.x * 256 + threadIdx.x;   // < 122880
    float v = bo[i % CS];
    #pragma unroll
    for (int ks = 0; ks < 5; ks++) v += part[(size_t)ks * 122880 + i];
    out[i] = v;
}

extern "C" void kernel_launch(void* const* d_in, const int* in_sizes, int n_in,
                              void* d_out, int out_size, void* d_ws, size_t ws_size,
                              hipStream_t stream)
{
    const float* s     = (const float*)d_in[0];
    const float* rot   = (const float*)d_in[1];
    const float* trans = (const float*)d_in[2];
    const float* z     = (const float*)d_in[3];
    const float* fm    = (const float*)d_in[4];
    const float* Wq    = (const float*)d_in[5];
    const float* bq    = (const float*)d_in[6];
    const float* Wkv   = (const float*)d_in[7];
    const float* bkv   = (const float*)d_in[8];
    const float* Wqp   = (const float*)d_in[9];
    const float* bqp   = (const float*)d_in[10];
    const float* Wkvp  = (const float*)d_in[11];
    const float* bkvp  = (const float*)d_in[12];
    const float* Wg    = (const float*)d_in[13];
    const float* bg    = (const float*)d_in[14];
    const float* gw    = (const float*)d_in[15];
    const float* dw    = (const float*)d_in[16];
    const float* hw    = (const float*)d_in[17];
    const float* Wo    = (const float*)d_in[18];
    const float* bo    = (const float*)d_in[19];

    float* ws = (float*)d_ws;
    float*          q       = ws + OFF_Q;
    float*          kv      = ws + OFF_KV;
    float*          qpt     = ws + OFF_QPT;
    float*          att     = ws + OFF_ATTHI;
    float*          part    = ws + OFF_PARTG;
    float*          cc      = ws + OFF_CCHI;
    unsigned short* s_hi    = (unsigned short*)(ws + OFF_SHI);
    unsigned short* s_mid   = (unsigned short*)(ws + OFF_SMID);
    unsigned short* s_lo    = (unsigned short*)(ws + OFF_SLO);
    float*          bcat    = ws + OFF_BCAT;
    unsigned short* vkv_hi  = (unsigned short*)(ws + OFF_VKVHI);
    unsigned short* vkv_lo  = (unsigned short*)(ws + OFF_VKVLO);
    float*          qpr     = ws + OFF_QPR;
    float*          kvpr    = ws + OFF_KVPR;
    float*          gate    = ws + OFF_GATE;
    float*          krowT   = ws + OFF_KROW;
    unsigned short* wcT_hi  = (unsigned short*)(ws + OFF_WCTHI);
    unsigned short* wcT_mid = (unsigned short*)(ws + OFF_WCTMID);
    unsigned short* wcT_lo  = (unsigned short*)(ws + OFF_WCTLO);
    unsigned short* woT_hi  = (unsigned short*)(ws + OFF_WOTHI);
    unsigned short* woT_lo  = (unsigned short*)(ws + OFF_WOTLO);
    float* out = (float*)d_out;

    k_prep<<<dim3(883), dim3(256), 0, stream>>>(s, Wq, bq, Wkv, bkv, Wqp, bqp,
                                                Wkvp, bkvp, Wg, bg, Wo,
                                                s_hi, s_mid, s_lo, bcat,
                                                wcT_hi, wcT_mid, wcT_lo, woT_hi, woT_lo);
    k_proj<<<dim3(37, 20), dim3(192), 0, stream>>>(s_hi, s_mid, s_lo, wcT_hi, wcT_mid, wcT_lo,
                                                   bcat, q, kv, qpr, kvpr, gate);
    k_points<<<dim3(LSEQ), dim3(256), 0, stream>>>(qpr, kvpr, gate, rot, trans, kv,
                                                   qpt, krowT, vkv_hi, vkv_lo);
    k_att<<<dim3(40, NH), dim3(256), 0, stream>>>(q, qpt, krowT, fm, gw, dw, hw, att);
    k_svpair<<<dim3(560), dim3(256), 0, stream>>>(att, vkv_hi, vkv_lo, z, rot, trans, cc);
    k_gemm<<<dim3(20, 6, 5), dim3(256), 0, stream>>>(cc, woT_hi, woT_lo, part);
    k_reduce<<<dim3(480), dim3(256), 0, stream>>>(part, bo, out);
}

// Round 11
// 201.362 us; speedup vs baseline: 1.1224x; 1.0208x over previous
//
#include <hip/hip_runtime.h>
#include <hip/hip_bf16.h>
#include <math.h>

#define LSEQ 320
#define CS 384
#define CZ 128
#define CH 16
#define NH 12
#define PQ 4
#define PV 8
#define EPSF 1e-8f

typedef short short8 __attribute__((ext_vector_type(8)));
typedef float f32x4 __attribute__((ext_vector_type(4)));
typedef unsigned short ush2 __attribute__((ext_vector_type(2)));

// float -> bf16 (RNE)
__device__ __forceinline__ unsigned short f2b(float x) {
    union { float f; unsigned u; } v; v.f = x;
    unsigned r = (v.u + 0x7FFF + ((v.u >> 16) & 1)) >> 16;
    return (unsigned short)r;
}
__device__ __forceinline__ float b2f(unsigned short h) {
    union { unsigned u; float f; } v; v.u = ((unsigned)h) << 16;
    return v.f;
}

// workspace float offsets
#define OFF_Q       0
#define OFF_KV      61440
#define OFF_QPT     184320
#define OFF_SHI     276480
#define OFF_SLO     399360
#define OFF_ATTHI   552960
#define OFF_PARTG   552960
#define OFF_CCHI    2191360
#define OFF_BCAT    4074496
#define OFF_VKVHI   4997872
#define OFF_VKVLO   5120752
#define OFF_QPR     5243632
#define OFF_KVPR    5335792
#define OFF_GATE    5612272
#define OFF_KROW    6242032
#define OFF_WCTHI   6426352
#define OFF_WCTLO   7108336
#define OFF_WOTHI   7449328
#define OFF_WOTLO   7910128

// ---------------- kernel 0: fused weight split/transpose + cast s + bcat ---------
// bid < 168: wc transpose (2-way split).  168..395: wo transpose.  else: s cast (2-way).
__global__ __launch_bounds__(256) void k_prep(
    const float* __restrict__ s,
    const float* __restrict__ Wq, const float* __restrict__ bq,
    const float* __restrict__ Wkv, const float* __restrict__ bkv,
    const float* __restrict__ Wqp, const float* __restrict__ bqp,
    const float* __restrict__ Wkvp, const float* __restrict__ bkvp,
    const float* __restrict__ Wg, const float* __restrict__ bg,
    const float* __restrict__ Wo,
    unsigned short* __restrict__ s_hi, unsigned short* __restrict__ s_lo,
    float* __restrict__ bcat,
    unsigned short* __restrict__ wcT_hi, unsigned short* __restrict__ wcT_lo,
    unsigned short* __restrict__ woT_hi, unsigned short* __restrict__ woT_lo)
{
    __shared__ unsigned short th[64][65], tl[64][65];
    int bid = blockIdx.x, tid = threadIdx.x;
    if (bid < 168) {
        int k0 = (bid % 6) * 64, c0 = (bid / 6) * 64;
        #pragma unroll
        for (int rep = 0; rep < 16; rep++) {
            int idx = rep * 256 + tid;
            int i = idx >> 6, j = idx & 63;    // i = k-off, j = c-off
            int c = c0 + j, k = k0 + i;
            float v = 0.f;
            if (c < 1776) {
                if (c < 192)       v = Wq[(size_t)k * 192 + c];
                else if (c < 576)  v = Wkv[(size_t)k * 384 + c - 192];
                else if (c < 864)  v = Wqp[(size_t)k * 288 + c - 576];
                else if (c < 1728) v = Wkvp[(size_t)k * 864 + c - 864];
                else               v = Wg[(size_t)k * 48 + c - 1728];
            }
            unsigned short hi = f2b(v);
            th[i][j] = hi; tl[i][j] = f2b(v - b2f(hi));
        }
        __syncthreads();
        #pragma unroll
        for (int rep = 0; rep < 16; rep++) {
            int idx = rep * 256 + tid;
            int i = idx >> 6, j = idx & 63;    // i = c-off, j = k-off
            int c = c0 + i;
            if (c < 1776) {
                size_t o = (size_t)c * 384 + k0 + j;
                wcT_hi[o] = th[j][i]; wcT_lo[o] = tl[j][i];
            }
        }
        return;
    }
    if (bid < 396) {
        int b = bid - 168;
        int r0 = (b % 38) * 64, c0 = (b / 38) * 64;
        #pragma unroll
        for (int rep = 0; rep < 16; rep++) {
            int idx = rep * 256 + tid;
            int i = idx >> 6, j = idx & 63;    // i = r-off, j = c-off
            int r = r0 + i;
            float v = 0.f;
            if (r < 2400) v = Wo[(size_t)r * 384 + c0 + j];
            unsigned short hi = f2b(v);
            th[i][j] = hi; tl[i][j] = f2b(v - b2f(hi));
        }
        __syncthreads();
        #pragma unroll
        for (int rep = 0; rep < 16; rep++) {
            int idx = rep * 256 + tid;
            int i = idx >> 6, j = idx & 63;    // i = c-off, j = r-off
            int r = r0 + j;
            if (r < 2400) {
                size_t o = (size_t)(c0 + i) * 2400 + r;
                woT_hi[o] = th[j][i]; woT_lo[o] = tl[j][i];
            }
        }
        return;
    }
    int i = (bid - 396) * 256 + tid;
    if (i < 122880) {
        float x = s[i];
        unsigned short hi = f2b(x);
        s_hi[i] = hi; s_lo[i] = f2b(x - b2f(hi));
        return;
    }
    i -= 122880;
    if (i < 1776) {
        float v;
        if (i < 192)       v = bq[i];
        else if (i < 576)  v = bkv[i - 192];
        else if (i < 864)  v = bqp[i - 576];
        else if (i < 1728) v = bkvp[i - 864];
        else               v = bg[i - 1728];
        bcat[i] = v;
    }
}

// ---------------- kernel 1: projection GEMM, 2-way split MFMA, m=16 tiles ---------
__global__ __launch_bounds__(192) void k_proj(
    const unsigned short* __restrict__ s_hi, const unsigned short* __restrict__ s_lo,
    const unsigned short* __restrict__ wcT_hi, const unsigned short* __restrict__ wcT_lo,
    const float* __restrict__ bcat,
    float* __restrict__ qo, float* __restrict__ kvo,
    float* __restrict__ qpr, float* __restrict__ kvpr, float* __restrict__ gate)
{
    __shared__ unsigned short a_h[16][56], a_l[16][56];
    __shared__ unsigned short w_h[48][56], w_l[48][56];
    int col0 = blockIdx.x * 48, l0 = blockIdx.y * 16;
    int tid = threadIdx.x;
    int lane = tid & 63, w = tid >> 6;
    int ncol = lane & 15, blk = lane >> 4, mrow = (lane >> 4) * 4;

    float* dst; int nc, cbase; bool sig = false;
    if (col0 < 192)       { nc = 192; cbase = col0;        dst = qo;   }
    else if (col0 < 576)  { nc = 384; cbase = col0 - 192;  dst = kvo;  }
    else if (col0 < 864)  { nc = 288; cbase = col0 - 576;  dst = qpr;  }
    else if (col0 < 1728) { nc = 864; cbase = col0 - 864;  dst = kvpr; }
    else                  { nc = 48;  cbase = 0;           dst = gate; sig = true; }

    f32x4 acc = {};
    for (int k0 = 0; k0 < 384; k0 += 32) {
        __syncthreads();
        if (tid < 128) {
            int arr = tid >> 6, idx = tid & 63;
            int row = idx >> 2, seg = idx & 3;
            size_t off = (size_t)(l0 + row) * 384 + k0 + seg * 8;
            if (arr == 0) *(short8*)&a_h[row][seg * 8] = *(const short8*)(s_hi + off);
            else          *(short8*)&a_l[row][seg * 8] = *(const short8*)(s_lo + off);
        }
        {
            int row = tid >> 2, seg = tid & 3;
            size_t off = (size_t)(col0 + row) * 384 + k0 + seg * 8;
            *(short8*)&w_h[row][seg * 8] = *(const short8*)(wcT_hi + off);
            *(short8*)&w_l[row][seg * 8] = *(const short8*)(wcT_lo + off);
        }
        __syncthreads();
        short8 afh = *(short8*)&a_h[ncol][blk * 8];
        short8 afl = *(short8*)&a_l[ncol][blk * 8];
        short8 bfh = *(short8*)&w_h[w * 16 + ncol][blk * 8];
        short8 bfl = *(short8*)&w_l[w * 16 + ncol][blk * 8];
        acc = __builtin_amdgcn_mfma_f32_16x16x32_bf16(afh, bfh, acc, 0, 0, 0);
        acc = __builtin_amdgcn_mfma_f32_16x16x32_bf16(afh, bfl, acc, 0, 0, 0);
        acc = __builtin_amdgcn_mfma_f32_16x16x32_bf16(afl, bfh, acc, 0, 0, 0);
    }
    {
        int n = w * 16 + ncol;
        float bv = bcat[col0 + n];
        int cloc = cbase + n;
        #pragma unroll
        for (int r = 0; r < 4; r++) {
            float v2 = acc[r] + bv;
            if (sig) v2 = 1.0f / (1.0f + expf(-v2));
            dst[(size_t)(l0 + mrow + r) * nc + cloc] = v2;
        }
    }
}

// ---------------- kernel 2: frame transforms + vkvT hi/lo + krowT table ----------
// krowT layout: [h][j][kk]  (j-major so k_att lane reads are coalesced)
__global__ __launch_bounds__(256) void k_points(
    const float* __restrict__ qpr, const float* __restrict__ kvpr, const float* __restrict__ gate,
    const float* __restrict__ rot, const float* __restrict__ trans,
    const float* __restrict__ kv,
    float* __restrict__ qpt, float* __restrict__ krowT,
    unsigned short* __restrict__ vkv_hi, unsigned short* __restrict__ vkv_lo)
{
    __shared__ float vsh[96][6];
    __shared__ float kp_s[48][6];
    __shared__ float kn_s[48];
    int l = blockIdx.x, t = threadIdx.x;
    const float* R = rot + l * 9;
    float tx = trans[l * 3], ty = trans[l * 3 + 1], tz = trans[l * 3 + 2];
    if (t < 192) {
        const float* src; float g = 1.0f; float* dst = nullptr; int vj = -1, kj = -1;
        if (t < 48)      { src = qpr + (size_t)l * 288 + t * 6; g = gate[l * 48 + t]; dst = qpt + ((size_t)l * 48 + t) * 6; }
        else if (t < 96) { kj = t - 48; src = kvpr + (size_t)l * 864 + kj * 6; }
        else             { int j = t - 96; src = kvpr + (size_t)l * 864 + 288 + j * 6; vj = j; }
        float px = src[0], py = src[1], pz = src[2], ux = src[3], uy = src[4], uz = src[5];
        float c0 = R[0] * px + R[1] * py + R[2] * pz + tx;
        float c1 = R[3] * px + R[4] * py + R[5] * pz + ty;
        float c2 = R[6] * px + R[7] * py + R[8] * pz + tz;
        float d0 = R[0] * ux + R[1] * uy + R[2] * uz;
        float d1 = R[3] * ux + R[4] * uy + R[5] * uz;
        float d2 = R[6] * ux + R[7] * uy + R[8] * uz;
        if (vj >= 0) {
            vsh[vj][0] = c0; vsh[vj][1] = c1; vsh[vj][2] = c2;
            vsh[vj][3] = d0; vsh[vj][4] = d1; vsh[vj][5] = d2;
        } else if (kj >= 0) {
            kp_s[kj][0] = c0; kp_s[kj][1] = c1; kp_s[kj][2] = c2;
            kp_s[kj][3] = d0; kp_s[kj][4] = d1; kp_s[kj][5] = d2;
            kn_s[kj] = sqrtf(d0 * d0 + d1 * d1 + d2 * d2);
        } else {
            dst[0] = c0 * g; dst[1] = c1 * g; dst[2] = c2 * g;
            dst[3] = d0 * g; dst[4] = d1 * g; dst[5] = d2 * g;
        }
    }
    __syncthreads();
    #pragma unroll
    for (int e = 0; e < 3; e++) {
        int u = t * 3 + e;   // < 768
        int h = u >> 6, n = u & 63;
        float val;
        if (n < 16) val = kv[(size_t)l * 384 + 192 + h * 16 + n];
        else        val = vsh[h * 8 + (n - 16) / 6][(n - 16) % 6];
        unsigned short hi = f2b(val);
        size_t idx = ((size_t)h * 64 + n) * 320 + l;
        vkv_hi[idx] = hi;
        vkv_lo[idx] = f2b(val - b2f(hi));
    }
    for (int idx = t; idx < 576; idx += 256) {
        int h = idx / 48, j = idx - h * 48;
        float v;
        if (j < 24)      v = kp_s[h * 4 + j / 6][j % 6];
        else if (j < 40) v = kv[(size_t)l * 384 + h * 16 + (j - 24)];
        else if (j < 44) v = kn_s[h * 4 + (j - 40)];
        else             v = 0.0f;
        krowT[((size_t)h * 48 + j) * 320 + l] = v;
    }
}

// ---------------- kernel 3: attention logits + softmax; coalesced krowT reads ----
__global__ __launch_bounds__(256) void k_att(
    const float* __restrict__ qb, const float* __restrict__ qpt,
    const float* __restrict__ krowT,
    const float* __restrict__ fm, const float* __restrict__ gw,
    const float* __restrict__ dwp, const float* __restrict__ hwp,
    float* __restrict__ att)
{
    int tid = threadIdx.x;
    int w = tid >> 6, lane = tid & 63;
    int iqA = blockIdx.x * 8 + w * 2;
    int iqB = iqA + 1;
    int h = blockIdx.y;

    float qvA[CH], qvB[CH];
    #pragma unroll
    for (int c = 0; c < CH; c++) {
        qvA[c] = qb[(size_t)iqA * 192 + h * CH + c];
        qvB[c] = qb[(size_t)iqB * 192 + h * CH + c];
    }
    float qpA[24], qpB[24];
    #pragma unroll
    for (int j = 0; j < 24; j++) {
        qpA[j] = qpt[(size_t)iqA * 288 + h * 24 + j];
        qpB[j] = qpt[(size_t)iqB * 288 + h * 24 + j];
    }
    float nqA[PQ], nq2A[PQ], nqB[PQ], nq2B[PQ];
    #pragma unroll
    for (int p = 0; p < PQ; p++) {
        float x = qpA[p * 6 + 3], y = qpA[p * 6 + 4], zz = qpA[p * 6 + 5];
        nq2A[p] = x * x + y * y + zz * zz; nqA[p] = sqrtf(nq2A[p]);
        x = qpB[p * 6 + 3]; y = qpB[p * 6 + 4]; zz = qpB[p * 6 + 5];
        nq2B[p] = x * x + y * y + zz * zz; nqB[p] = sqrtf(nq2B[p]);
    }
    float dwv = dwp[0], g0 = gw[0], g1 = gw[1], hwv = hwp[h];
    float fmA = fm[iqA], fmB = fm[iqB];

    float lgA[5], lgB[5];
    for (int r = 0; r < 5; r++) {
        int kk = r * 64 + lane;
        const float* colp = krowT + (size_t)h * 48 * 320 + kk;
        float rw[44];
        #pragma unroll
        for (int j = 0; j < 44; j++) rw[j] = colp[(size_t)j * 320];
        float fmk = fm[kk];

        #pragma unroll
        for (int which = 0; which < 2; which++) {
            const float* qp = which ? qpB : qpA;
            const float* qv = which ? qvB : qvA;
            const float* nq = which ? nqB : nqA;
            const float* nq2 = which ? nq2B : nq2A;
            float fmi = which ? fmB : fmA;

            float scalar = 0.f;
            #pragma unroll
            for (int c = 0; c < CH; c++) scalar += qv[c] * rw[24 + c];
            scalar *= 0.25f;

            float pos = 0.f;
            #pragma unroll
            for (int p = 0; p < PQ; p++) {
                float dx = qp[p * 6] - rw[p * 6];
                float dy = qp[p * 6 + 1] - rw[p * 6 + 1];
                float dz = qp[p * 6 + 2] - rw[p * 6 + 2];
                float d = __builtin_amdgcn_sqrtf(dx * dx + dy * dy + dz * dz);
                float de = d + EPSF;
                pos += d + __logf(de) + __builtin_amdgcn_rcpf(de);
            }
            pos *= 0.25f;

            float dir = 0.f;
            #pragma unroll
            for (int p = 0; p < PQ; p++) {
                float kx = rw[p * 6 + 3], ky = rw[p * 6 + 4], kz = rw[p * 6 + 5];
                float nk = rw[40 + p];
                float nk2 = nk * nk;
                float cm = 0.f, dself = 0.f;
                #pragma unroll
                for (int pq = 0; pq < PQ; pq++) {
                    float dq = qp[pq * 6 + 3] * kx + qp[pq * 6 + 4] * ky + qp[pq * 6 + 5] * kz;
                    if (pq == p) dself = dq;
                    cm += __builtin_amdgcn_sqrtf(fmaxf(nq2[pq] * nk2 - dq * dq, 0.0f));
                }
                cm *= 0.25f;
                dir += dself - cm * __builtin_amdgcn_rcpf(nq[p] * nk + EPSF);
            }
            dir *= 0.25f;

            float logit = scalar + dwv * (g0 * pos + g1 * dir);
            logit *= hwv;
            logit += 100000.0f * (fmi * fmk - 1.0f);
            if (which) lgB[r] = logit; else lgA[r] = logit;
        }
    }

    // softmax A
    float mxA = lgA[0];
    #pragma unroll
    for (int r = 1; r < 5; r++) mxA = fmaxf(mxA, lgA[r]);
    for (int m = 32; m; m >>= 1) mxA = fmaxf(mxA, __shfl_xor(mxA, m, 64));
    float eA[5], smA = 0.f;
    #pragma unroll
    for (int r = 0; r < 5; r++) { eA[r] = __expf(lgA[r] - mxA); smA += eA[r]; }
    for (int m = 32; m; m >>= 1) smA += __shfl_xor(smA, m, 64);
    float invA = 1.0f / smA;
    #pragma unroll
    for (int r = 0; r < 5; r++)
        att[((size_t)h * 320 + iqA) * 320 + r * 64 + lane] = eA[r] * invA;
    // softmax B
    float mxB = lgB[0];
    #pragma unroll
    for (int r = 1; r < 5; r++) mxB = fmaxf(mxB, lgB[r]);
    for (int m = 32; m; m >>= 1) mxB = fmaxf(mxB, __shfl_xor(mxB, m, 64));
    float eB[5], smB = 0.f;
    #pragma unroll
    for (int r = 0; r < 5; r++) { eB[r] = __expf(lgB[r] - mxB); smB += eB[r]; }
    for (int m = 32; m; m >>= 1) smB += __shfl_xor(smB, m, 64);
    float invB = 1.0f / smB;
    #pragma unroll
    for (int r = 0; r < 5; r++)
        att[((size_t)h * 320 + iqB) * 320 + r * 64 + lane] = eB[r] * invB;
}

// ---------------- kernel 4: fused pair (bid<320, heavy first) + sv (bid>=320) ----
__global__ __launch_bounds__(256) void k_svpair(
    const float* __restrict__ att,   // [12][320][320]
    const unsigned short* __restrict__ vkv_hi, const unsigned short* __restrict__ vkv_lo,
    const float* __restrict__ z,     // [320][320][128]
    const float* __restrict__ rot, const float* __restrict__ trans,
    float* __restrict__ cc)          // [320][2400]
{
    __shared__ unsigned short a_hi[16][56];
    __shared__ unsigned short a_lo[16][56];
    __shared__ unsigned short B[128][56];
    __shared__ float ogsh[16][49];
    int bid = blockIdx.x;
    int tid = threadIdx.x;
    int lane = tid & 63, w = tid >> 6;
    int ncol = lane & 15, blk = lane >> 4, mrow = (lane >> 4) * 4;

    if (bid < 320) {
        int iq = bid;
        int kp2 = (tid & 15) * 2;
        int cb = (tid >> 4) * 8;
        const float* zbase = z + ((size_t)iq * 320 + kp2) * 128 + cb;

        float4 zA0, zA1, zA2, zA3, zB0, zB1, zB2, zB3;
        {
            const float* p = zbase;
            zA0 = *(const float4*)(p);       zA1 = *(const float4*)(p + 4);
            zA2 = *(const float4*)(p + 128); zA3 = *(const float4*)(p + 132);
            p = zbase + (size_t)32 * 128;
            zB0 = *(const float4*)(p);       zB1 = *(const float4*)(p + 4);
            zB2 = *(const float4*)(p + 128); zB3 = *(const float4*)(p + 132);
        }

        f32x4 acc[2] = {};
        #pragma unroll
        for (int i = 0; i < 10; i++) {
            int k0 = i * 32;
            __syncthreads();
            {
                int row = tid >> 4, c2 = (tid & 15) * 2;
                float v0 = 0.f, v1 = 0.f;
                if (row < 12) {
                    const float* ap = att + ((size_t)row * 320 + iq) * 320 + k0 + c2;
                    v0 = ap[0]; v1 = ap[1];
                }
                ush2 h2, l2;
                h2[0] = f2b(v0); l2[0] = f2b(v0 - b2f(h2[0]));
                h2[1] = f2b(v1); l2[1] = f2b(v1 - b2f(h2[1]));
                *(ush2*)&a_hi[row][c2] = h2;
                *(ush2*)&a_lo[row][c2] = l2;
            }
            {
                float va[8], vb[8];
                if ((i & 1) == 0) {
                    va[0]=zA0.x; va[1]=zA0.y; va[2]=zA0.z; va[3]=zA0.w;
                    va[4]=zA1.x; va[5]=zA1.y; va[6]=zA1.z; va[7]=zA1.w;
                    vb[0]=zA2.x; vb[1]=zA2.y; vb[2]=zA2.z; vb[3]=zA2.w;
                    vb[4]=zA3.x; vb[5]=zA3.y; vb[6]=zA3.z; vb[7]=zA3.w;
                } else {
                    va[0]=zB0.x; va[1]=zB0.y; va[2]=zB0.z; va[3]=zB0.w;
                    va[4]=zB1.x; va[5]=zB1.y; va[6]=zB1.z; va[7]=zB1.w;
                    vb[0]=zB2.x; vb[1]=zB2.y; vb[2]=zB2.z; vb[3]=zB2.w;
                    vb[4]=zB3.x; vb[5]=zB3.y; vb[6]=zB3.z; vb[7]=zB3.w;
                }
                #pragma unroll
                for (int c = 0; c < 8; c++) {
                    ush2 pr;
                    pr[0] = f2b(va[c]);
                    pr[1] = f2b(vb[c]);
                    *(ush2*)&B[cb + c][kp2] = pr;
                }
                if (i + 2 < 10) {
                    const float* p = zbase + (size_t)(k0 + 64) * 128;
                    if ((i & 1) == 0) {
                        zA0 = *(const float4*)(p);       zA1 = *(const float4*)(p + 4);
                        zA2 = *(const float4*)(p + 128); zA3 = *(const float4*)(p + 132);
                    } else {
                        zB0 = *(const float4*)(p);       zB1 = *(const float4*)(p + 4);
                        zB2 = *(const float4*)(p + 128); zB3 = *(const float4*)(p + 132);
                    }
                }
            }
            __syncthreads();
            short8 afh = *(short8*)&a_hi[ncol][blk * 8];
            short8 afl = *(short8*)&a_lo[ncol][blk * 8];
            #pragma unroll
            for (int s2 = 0; s2 < 2; s2++) {
                short8 bf = *(short8*)&B[w * 32 + s2 * 16 + ncol][blk * 8];
                acc[s2] = __builtin_amdgcn_mfma_f32_16x16x32_bf16(afl, bf, acc[s2], 0, 0, 0);
                acc[s2] = __builtin_amdgcn_mfma_f32_16x16x32_bf16(afh, bf, acc[s2], 0, 0, 0);
            }
        }
        #pragma unroll
        for (int s2 = 0; s2 < 2; s2++) {
            int n = w * 32 + s2 * 16 + ncol;
            #pragma unroll
            for (int r = 0; r < 4; r++) {
                int h = mrow + r;
                if (h < 12)
                    cc[(size_t)iq * 2400 + 864 + (size_t)h * 128 + n] = acc[s2][r];
            }
        }
    } else {
        int b = bid - 320;
        int iq0 = (b % 20) * 16, h = b / 20;
        f32x4 acc = {};
        for (int k0 = 0; k0 < 320; k0 += 32) {
            __syncthreads();
            {
                int row = tid >> 4, c2 = (tid & 15) * 2;
                const float* ap = att + ((size_t)h * 320 + iq0 + row) * 320 + k0 + c2;
                float v0 = ap[0], v1 = ap[1];
                ush2 h2, l2;
                h2[0] = f2b(v0); l2[0] = f2b(v0 - b2f(h2[0]));
                h2[1] = f2b(v1); l2[1] = f2b(v1 - b2f(h2[1]));
                *(ush2*)&a_hi[row][c2] = h2;
                *(ush2*)&a_lo[row][c2] = l2;
            }
            {
                int row = tid >> 2, seg = tid & 3;
                size_t off = ((size_t)h * 64 + row) * 320 + k0 + seg * 8;
                *(short8*)&B[row][seg * 8]      = *(const short8*)(vkv_hi + off);
                *(short8*)&B[64 + row][seg * 8] = *(const short8*)(vkv_lo + off);
            }
            __syncthreads();
            short8 afh = *(short8*)&a_hi[ncol][blk * 8];
            short8 afl = *(short8*)&a_lo[ncol][blk * 8];
            short8 bfh = *(short8*)&B[w * 16 + ncol][blk * 8];
            short8 bfl = *(short8*)&B[64 + w * 16 + ncol][blk * 8];
            acc = __builtin_amdgcn_mfma_f32_16x16x32_bf16(afh, bfh, acc, 0, 0, 0);
            acc = __builtin_amdgcn_mfma_f32_16x16x32_bf16(afh, bfl, acc, 0, 0, 0);
            acc = __builtin_amdgcn_mfma_f32_16x16x32_bf16(afl, bfh, acc, 0, 0, 0);
        }
        {
            int n = w * 16 + ncol;
            #pragma unroll
            for (int r = 0; r < 4; r++) {
                int iq = iq0 + mrow + r;
                float v = acc[r];
                if (n < 16) cc[(size_t)iq * 2400 + h * 16 + n] = v;
                else        ogsh[mrow + r][n - 16] = v;
            }
        }
        __syncthreads();
        if (tid < 128) {
            int iqr = tid >> 3, p = tid & 7;
            int l = iq0 + iqr;
            const float* R = rot + l * 9;
            float tx = trans[l * 3], ty = trans[l * 3 + 1], tz = trans[l * 3 + 2];
            const float* o = &ogsh[iqr][p * 6];
            float gx = o[0] - tx, gy = o[1] - ty, gz = o[2] - tz;
            float l0 = R[0] * gx + R[3] * gy + R[6] * gz;
            float l1 = R[1] * gx + R[4] * gy + R[7] * gz;
            float l2 = R[2] * gx + R[5] * gy + R[8] * gz;
            float dx = o[3], dy = o[4], dz = o[5];
            float e0 = R[0] * dx + R[3] * dy + R[6] * dz;
            float e1 = R[1] * dx + R[4] * dy + R[7] * dz;
            float e2 = R[2] * dx + R[5] * dy + R[8] * dz;
            float n = sqrtf(e0 * e0 + e1 * e1 + e2 * e2);
            float inv = 1.0f / fmaxf(n, 1e-12f);
            float ln = sqrtf(l0 * l0 + l1 * l1 + l2 * l2);
            float vals[7] = { l0, l1, l2, e0 * inv, e1 * inv, e2 * inv, ln };
            size_t base = (size_t)l * 2400 + 192 + (h * PV + p) * 7;
            #pragma unroll
            for (int j = 0; j < 7; j++) cc[base + j] = vals[j];
        }
    }
}

// ---------------- kernel 5: partials = cc @ Wo; A split in-kernel ----------------
__global__ __launch_bounds__(256) void k_gemm(
    const float* __restrict__ cc,
    const unsigned short* __restrict__ woT_hi, const unsigned short* __restrict__ woT_lo,
    float* __restrict__ part)
{
    __shared__ unsigned short a_h[16][56], a_l[16][56];
    __shared__ unsigned short w_h[64][56], w_l[64][56];
    int iq0 = blockIdx.x * 16, col0 = blockIdx.y * 64, ks = blockIdx.z;
    int tid = threadIdx.x;
    int lane = tid & 63, w = tid >> 6;
    int ncol = lane & 15, blk = lane >> 4, mrow = (lane >> 4) * 4;

    f32x4 acc = {};
    for (int kc = 0; kc < 15; kc++) {
        int k0 = ks * 480 + kc * 32;
        __syncthreads();
        {
            int row = tid >> 4, c2 = (tid & 15) * 2;
            const float* ap = cc + (size_t)(iq0 + row) * 2400 + k0 + c2;
            float v0 = ap[0], v1 = ap[1];
            ush2 h2, l2;
            h2[0] = f2b(v0); l2[0] = f2b(v0 - b2f(h2[0]));
            h2[1] = f2b(v1); l2[1] = f2b(v1 - b2f(h2[1]));
            *(ush2*)&a_h[row][c2] = h2;
            *(ush2*)&a_l[row][c2] = l2;
        }
        #pragma unroll
        for (int t2 = 0; t2 < 2; t2++) {
            int idx = tid * 2 + t2;          // 0..511
            int arr = idx >> 8, i2 = idx & 255;
            int row = i2 >> 2, seg = i2 & 3;
            size_t off = (size_t)(col0 + row) * 2400 + k0 + seg * 8;
            if (arr == 0) *(short8*)&w_h[row][seg * 8] = *(const short8*)(woT_hi + off);
            else          *(short8*)&w_l[row][seg * 8] = *(const short8*)(woT_lo + off);
        }
        __syncthreads();
        short8 afh = *(short8*)&a_h[ncol][blk * 8];
        short8 afl = *(short8*)&a_l[ncol][blk * 8];
        short8 bfh = *(short8*)&w_h[w * 16 + ncol][blk * 8];
        short8 bfl = *(short8*)&w_l[w * 16 + ncol][blk * 8];
        acc = __builtin_amdgcn_mfma_f32_16x16x32_bf16(afh, bfh, acc, 0, 0, 0);
        acc = __builtin_amdgcn_mfma_f32_16x16x32_bf16(afh, bfl, acc, 0, 0, 0);
        acc = __builtin_amdgcn_mfma_f32_16x16x32_bf16(afl, bfh, acc, 0, 0, 0);
    }
    {
        int cn = col0 + w * 16 + ncol;
        #pragma unroll
        for (int r = 0; r < 4; r++)
            part[((size_t)ks * 320 + iq0 + mrow + r) * 384 + cn] = acc[r];
    }
}

// ---------------- kernel 6: out = bo + sum of 5 partials (deterministic) ----------
__global__ __launch_bounds__(256) void k_reduce(
    const float* __restrict__ part, const float* __restrict__ bo, float* __restrict__ out)
{
    int i = blockIdx.x * 256 + threadIdx.x;   // < 122880
    float v = bo[i % CS];
    #pragma unroll
    for (int ks = 0; ks < 5; ks++) v += part[(size_t)ks * 122880 + i];
    out[i] = v;
}

extern "C" void kernel_launch(void* const* d_in, const int* in_sizes, int n_in,
                              void* d_out, int out_size, void* d_ws, size_t ws_size,
                              hipStream_t stream)
{
    const float* s     = (const float*)d_in[0];
    const float* rot   = (const float*)d_in[1];
    const float* trans = (const float*)d_in[2];
    const float* z     = (const float*)d_in[3];
    const float* fm    = (const float*)d_in[4];
    const float* Wq    = (const float*)d_in[5];
    const float* bq    = (const float*)d_in[6];
    const float* Wkv   = (const float*)d_in[7];
    const float* bkv   = (const float*)d_in[8];
    const float* Wqp   = (const float*)d_in[9];
    const float* bqp   = (const float*)d_in[10];
    const float* Wkvp  = (const float*)d_in[11];
    const float* bkvp  = (const float*)d_in[12];
    const float* Wg    = (const float*)d_in[13];
    const float* bg    = (const float*)d_in[14];
    const float* gw    = (const float*)d_in[15];
    const float* dw    = (const float*)d_in[16];
    const float* hw    = (const float*)d_in[17];
    const float* Wo    = (const float*)d_in[18];
    const float* bo    = (const float*)d_in[19];

    float* ws = (float*)d_ws;
    float*          q       = ws + OFF_Q;
    float*          kv      = ws + OFF_KV;
    float*          qpt     = ws + OFF_QPT;
    float*          att     = ws + OFF_ATTHI;
    float*          part    = ws + OFF_PARTG;
    float*          cc      = ws + OFF_CCHI;
    unsigned short* s_hi    = (unsigned short*)(ws + OFF_SHI);
    unsigned short* s_lo    = (unsigned short*)(ws + OFF_SLO);
    float*          bcat    = ws + OFF_BCAT;
    unsigned short* vkv_hi  = (unsigned short*)(ws + OFF_VKVHI);
    unsigned short* vkv_lo  = (unsigned short*)(ws + OFF_VKVLO);
    float*          qpr     = ws + OFF_QPR;
    float*          kvpr    = ws + OFF_KVPR;
    float*          gate    = ws + OFF_GATE;
    float*          krowT   = ws + OFF_KROW;
    unsigned short* wcT_hi  = (unsigned short*)(ws + OFF_WCTHI);
    unsigned short* wcT_lo  = (unsigned short*)(ws + OFF_WCTLO);
    unsigned short* woT_hi  = (unsigned short*)(ws + OFF_WOTHI);
    unsigned short* woT_lo  = (unsigned short*)(ws + OFF_WOTLO);
    float* out = (float*)d_out;

    k_prep<<<dim3(883), dim3(256), 0, stream>>>(s, Wq, bq, Wkv, bkv, Wqp, bqp,
                                                Wkvp, bkvp, Wg, bg, Wo,
                                                s_hi, s_lo, bcat,
                                                wcT_hi, wcT_lo, woT_hi, woT_lo);
    k_proj<<<dim3(37, 20), dim3(192), 0, stream>>>(s_hi, s_lo, wcT_hi, wcT_lo,
                                                   bcat, q, kv, qpr, kvpr, gate);
    k_points<<<dim3(LSEQ), dim3(256), 0, stream>>>(qpr, kvpr, gate, rot, trans, kv,
                                                   qpt, krowT, vkv_hi, vkv_lo);
    k_att<<<dim3(40, NH), dim3(256), 0, stream>>>(q, qpt, krowT, fm, gw, dw, hw, att);
    k_svpair<<<dim3(560), dim3(256), 0, stream>>>(att, vkv_hi, vkv_lo, z, rot, trans, cc);
    k_gemm<<<dim3(20, 6, 5), dim3(256), 0, stream>>>(cc, woT_hi, woT_lo, part);
    k_reduce<<<dim3(480), dim3(256), 0, stream>>>(part, bo, out);
}